// Round 6
// baseline (311.651 us; speedup 1.0000x reference)
//
#include <hip/hip_runtime.h>
#include <hip/hip_bf16.h>

// Problem constants
#define NB 16
#define SS 7500
#define HH 64
#define TT 300
#define NHEAD 4
#define DKV 64
#define NJ 25
#define HDW 256
#define NQT 19
#define NST 10       // s-tiles of 32

typedef __attribute__((ext_vector_type(8))) short short8;
typedef __attribute__((ext_vector_type(4))) short s16x4;
typedef __attribute__((ext_vector_type(4))) float f32x4;

__device__ inline short f2bf(float f) {
    union { float f; unsigned u; } x; x.f = f;
    unsigned u = x.u + 0x7FFFu + ((x.u >> 16) & 1u);
    return (short)(u >> 16);
}
__device__ inline unsigned pk2(float a, float b) {  // packed fp32x2 -> bf16x2
    __hip_bfloat162 h = __float22bfloat162_rn(make_float2(a, b));
    union { __hip_bfloat162 h; unsigned u; } c; c.h = h; return c.u;
}
#define MFMA32(a, b, c) __builtin_amdgcn_mfma_f32_16x16x32_bf16((a), (b), (c), 0, 0, 0)
#define LGKM_BAR() asm volatile("s_waitcnt lgkmcnt(0)" ::: "memory")

__device__ __forceinline__ short8 pks8(unsigned a, unsigned b, unsigned c2, unsigned d) {
    union { uint4 u; short8 s; } c; c.u.x = a; c.u.y = b; c.u.z = c2; c.u.w = d; return c.s;
}
__device__ __forceinline__ short8 cat8(s16x4 a, s16x4 b) {
    return __builtin_shufflevector(a, b, 0, 1, 2, 3, 4, 5, 6, 7);
}
__device__ __forceinline__ short8 packx(const float* px) {
    const float4 x0 = *(const float4*)px;
    const float4 x1 = *(const float4*)(px + 4);
    union { uint4 u; short8 s; } cv;
    cv.u.x = pk2(x0.x, x0.y); cv.u.y = pk2(x0.z, x0.w);
    cv.u.z = pk2(x1.x, x1.y); cv.u.w = pk2(x1.z, x1.w);
    return cv.s;
}

// ws layout (bf16 units): QKV B-frags (96 frags x 512 shorts) + Wo K=16 frags
// (64 frags x 256 shorts). 131072 bytes total.
#define WS_BYTES ((size_t)65536 * 2)
#define WOBASE 49152

// ---------------- A0: weights -> bf16 fragment arrays ----------------
__global__ void wfrag_kernel(const float* __restrict__ Wq, const float* __restrict__ Wk,
                             const float* __restrict__ Wv, const float* __restrict__ Wo,
                             unsigned short* __restrict__ ws) {
    const int f = blockIdx.x;
    const int lane = threadIdx.x;
    const int L15 = lane & 15, quad = lane >> 4;
    if (f < 96) {
        const int matid = f >> 5, nt = (f & 31) >> 1, kt = f & 1;
        const float* W = matid == 0 ? Wq : (matid == 1 ? Wk : Wv);
        const int n = nt * 16 + L15;
        unsigned short* dst = ws + f * 512 + lane * 8;
        #pragma unroll
        for (int i = 0; i < 8; ++i)
            dst[i] = (unsigned short)f2bf(W[(kt * 32 + quad * 8 + i) * HDW + n]);
    } else {
        const int g = f - 96, nt = g & 3, kt = g >> 2;
        const int n = nt * 16 + L15;
        unsigned short* dst = ws + WOBASE + g * 256 + lane * 4;
        #pragma unroll
        for (int i = 0; i < 4; ++i)
            dst[i] = (unsigned short)f2bf(Wo[(kt * 16 + quad * 4 + i) * HH + n]);
    }
}

// ---------------- fully fused: proj + attention + out-proj ----------------
// 640 threads (10 waves), SINGLE-buffered sK/sV (79360 B) => 2 blocks/CU:
// all 400 blocks co-resident in ONE round (the R5 155KB dbuf forced 1
// block/CU => 2 serialized grid rounds, ~22% idle tail, and no second block
// to fill barrier stalls). Cross-block TLP now provides the overlap the
// dbuf used to, at half the LDS. setprio removed (pins instr order, blocks
// compiler pipelining; null-to-negative in barrier-lockstep structures).
// KEY IDENTITY: MFMA32(cat(a1,a2), cat(b1,b2)) == MFMA16(a1,b1)+MFMA16(a2,b2)
// => all K=16 fragment pairs are concatenated in-lane and fed to K=32 MFMA.
// K/V/Q input rows are head-invariant: loaded+packed ONCE into registers.
// sK[row][64]: K'^T rows; 16-short blocks XOR-swizzled by (row&3).
// sV[d][320]: V'^T; blocks (st*2 + quad>>1) XOR (d&3).
// __launch_bounds__(640,4): 128-reg cap (R5 used 84; 2-block residency
// needs <=102). Spill tripwire: WRITE_SIZE must stay ~30MB.

__device__ __forceinline__ void proj_kv(const short8 xf[4][2],
                                        const unsigned short* __restrict__ wf, int hp,
                                        unsigned short* __restrict__ dK, unsigned short* __restrict__ dV,
                                        int w, int lane, int L15, int quad) {
    // 40 job slots over 10 waves (4 each); jb>=38 are naturally store-masked dummies
    #pragma unroll
    for (int i = 0; i < 4; ++i) {
        const int jb = w + 10 * i;
        const int isV = jb >= 19;
        const int t = isV ? jb - 19 : jb;
        const unsigned short* mb = wf + (isV ? 2 : 1) * 16384;
        if (!isV) {
            const int s = t * 16 + L15;   // unclamped store row
            #pragma unroll
            for (int ntl = 0; ntl < 4; ++ntl) {
                const short8 b0 = *(const short8*)&mb[((hp * 4 + ntl) * 2 + 0) * 512 + lane * 8];
                const short8 b1 = *(const short8*)&mb[((hp * 4 + ntl) * 2 + 1) * 512 + lane * 8];
                f32x4 c = {0.f, 0.f, 0.f, 0.f};
                c = MFMA32(b0, xf[i][0], c);   // A=W => C = K'^T[d'][s], s on L15
                c = MFMA32(b1, xf[i][1], c);
                if (s < TT) {
                    uint2 pkd; pkd.x = pk2(c[0], c[1]); pkd.y = pk2(c[2], c[3]);
                    const int pp = ntl >> 1, oo = ntl & 1;
                    const int blk = ((pp << 1) | (quad >> 1)) ^ (s & 3);
                    *(uint2*)&dK[s * 64 + (blk << 4) + ((quad & 1) << 3) + (oo << 2)] = pkd;
                }
            }
        } else {
            const int sb = t * 16 + quad * 4;
            const int stv = t >> 1, rhv = t & 1;
            #pragma unroll
            for (int ntl = 0; ntl < 4; ++ntl) {
                const short8 b0 = *(const short8*)&mb[((hp * 4 + ntl) * 2 + 0) * 512 + lane * 8];
                const short8 b1 = *(const short8*)&mb[((hp * 4 + ntl) * 2 + 1) * 512 + lane * 8];
                f32x4 c = {0.f, 0.f, 0.f, 0.f};
                c = MFMA32(xf[i][0], b0, c);   // A=x => C = V'[s][d], d on L15
                c = MFMA32(xf[i][1], b1, c);
                if (sb < TT) {
                    const int d = ntl * 16 + L15;
                    uint2 pkd; pkd.x = pk2(c[0], c[1]); pkd.y = pk2(c[2], c[3]);
                    const int blk = ((stv << 1) | (quad >> 1)) ^ (d & 3);
                    *(uint2*)&dV[d * 320 + (blk << 4) + ((quad & 1) << 3) + (rhv << 2)] = pkd;
                }
            }
        }
    }
}

// Q' projection -> two concatenated K=32 B-frags (qa8[0] pairs with sK's k0
// chunk, qa8[1] with k1); scale 1/8 folded.
__device__ __forceinline__ void qproj_reg(const short8 qx[2],
                                          const unsigned short* __restrict__ wf,
                                          int h, short8* qa8, int lane) {
    #pragma unroll
    for (int p = 0; p < 2; ++p) {
        unsigned pkv[4];
        #pragma unroll
        for (int hf = 0; hf < 2; ++hf) {
            const int ntl = 2 * p + hf;
            const short8 b0 = *(const short8*)&wf[((h * 4 + ntl) * 2 + 0) * 512 + lane * 8];
            const short8 b1 = *(const short8*)&wf[((h * 4 + ntl) * 2 + 1) * 512 + lane * 8];
            f32x4 c = {0.f, 0.f, 0.f, 0.f};
            c = MFMA32(b0, qx[0], c);   // A=W (swapped) => C = Q'^T[d'][q], q on L15
            c = MFMA32(b1, qx[1], c);
            pkv[2 * hf + 0] = pk2(c[0] * 0.125f, c[1] * 0.125f);
            pkv[2 * hf + 1] = pk2(c[2] * 0.125f, c[3] * 0.125f);
        }
        qa8[p] = pks8(pkv[0], pkv[1], pkv[2], pkv[3]);
    }
}

__device__ __forceinline__ void attn_pass2(const unsigned short* __restrict__ sK,
                                           const unsigned short* __restrict__ sV,
                                           const short8 qa8[2][2], f32x4 oT[2][4],
                                           float* __restrict__ lsum,
                                           int L15, int quad) {
    #pragma unroll 2
    for (int st = 0; st < NST; ++st) {
        unsigned ptw[2][4];
        #pragma unroll
        for (int rh = 0; rh < 2; ++rh) {
            int row = st * 32 + rh * 16 + L15; if (row > TT - 1) row = TT - 1;
            const int rb = row * 64 + ((quad & 1) << 3);
            const short8 k0 = *(const short8*)&sK[rb + ((((quad >> 1) | 0) ^ (row & 3)) << 4)];
            const short8 k1 = *(const short8*)&sK[rb + ((((quad >> 1) | 2) ^ (row & 3)) << 4)];
            #pragma unroll
            for (int su = 0; su < 2; ++su) {
                f32x4 c = {0.f, 0.f, 0.f, 0.f};
                c = MFMA32(k0, qa8[su][0], c);
                c = MFMA32(k1, qa8[su][1], c);
                if (st == NST - 1) {      // mask s >= 300 (s = 288+rh*16+quad*4+rr)
                    if (rh == 1 || quad == 3) {
                        c[0] = -1e38f; c[1] = -1e38f; c[2] = -1e38f; c[3] = -1e38f;
                    }
                }
                // fixed-max softmax p=exp(s-16); exact after 1/l
                const float p0 = __expf(c[0] - 16.f);
                const float p1 = __expf(c[1] - 16.f);
                const float p2 = __expf(c[2] - 16.f);
                const float p3 = __expf(c[3] - 16.f);
                lsum[su] += (p0 + p1) + (p2 + p3);
                ptw[su][2 * rh + 0] = pk2(p0, p1);
                ptw[su][2 * rh + 1] = pk2(p2, p3);
            }
        }
        const short8 pa0 = pks8(ptw[0][0], ptw[0][1], ptw[0][2], ptw[0][3]);
        const short8 pa1 = pks8(ptw[1][0], ptw[1][1], ptw[1][2], ptw[1][3]);
        #pragma unroll
        for (int nt = 0; nt < 4; ++nt) {
            const int d = nt * 16 + L15;
            const int blk = ((st << 1) | (quad >> 1)) ^ (d & 3);
            const short8 vp = *(const short8*)&sV[d * 320 + (blk << 4) + ((quad & 1) << 3)];
            oT[0][nt] = MFMA32(vp, pa0, oT[0][nt]);
            oT[1][nt] = MFMA32(vp, pa1, oT[1][nt]);
        }
    }
}

__device__ __forceinline__ void epilogue(const unsigned short* __restrict__ wf, int h,
                                         float lsum, const f32x4* oT, f32x4* y, int lane) {
    lsum += __shfl_xor(lsum, 16);
    lsum += __shfl_xor(lsum, 32);
    const float linv = 1.f / lsum;
    short8 oa8[2];   // in-lane A-frag packs, kc pairs concatenated to K=32
    #pragma unroll
    for (int p = 0; p < 2; ++p)
        oa8[p] = pks8(pk2(oT[2 * p][0] * linv, oT[2 * p][1] * linv),
                      pk2(oT[2 * p][2] * linv, oT[2 * p][3] * linv),
                      pk2(oT[2 * p + 1][0] * linv, oT[2 * p + 1][1] * linv),
                      pk2(oT[2 * p + 1][2] * linv, oT[2 * p + 1][3] * linv));
    #pragma unroll
    for (int nc = 0; nc < 4; ++nc) {
        #pragma unroll
        for (int p = 0; p < 2; ++p) {
            const s16x4 w0 = *(const s16x4*)&wf[WOBASE + (((h * 4 + 2 * p + 0) * 4 + nc) << 8) + (lane << 2)];
            const s16x4 w1 = *(const s16x4*)&wf[WOBASE + (((h * 4 + 2 * p + 1) * 4 + nc) << 8) + (lane << 2)];
            y[nc] = MFMA32(oa8[p], cat8(w0, w1), y[nc]);
        }
    }
}

__device__ __forceinline__ void store_tile(float* __restrict__ out, long xbase, int tile,
                                           const f32x4* y, int L15, int quad) {
    #pragma unroll
    for (int nc = 0; nc < 4; ++nc)
        #pragma unroll
        for (int rr = 0; rr < 4; ++rr) {
            const int row = tile * 16 + quad * 4 + rr;
            if (row < TT)
                out[xbase + (long)row * HH + nc * 16 + L15] = y[nc][rr];
        }
}

__global__ __launch_bounds__(640, 4)
void attn9(const float* __restrict__ q, const float* __restrict__ k,
           const float* __restrict__ v, const unsigned short* __restrict__ wf,
           float* __restrict__ out)
{
    __shared__ __align__(16) unsigned short sK[19200];   // 38400 B
    __shared__ __align__(16) unsigned short sV[20480];   // 40960 B

    const int tid = threadIdx.x;
    const int w = tid >> 6, lane = tid & 63;
    const int L15 = lane & 15, quad = lane >> 4;
    const int bj = blockIdx.x;
    const int b = bj / NJ, j = bj % NJ;
    const long xbase = ((long)b * SS + (long)j * TT) * HH;

    // zero V pad (logical s 288..319 of st=9; valid parts rewritten each head)
    for (int i = tid; i < 2048; i += 640) {
        const int d = i >> 5, off = 288 + (i & 31);
        const int blk = (off >> 4) ^ (d & 3);
        sV[d * 320 + (blk << 4) + (off & 15)] = 0;
    }

    // hoisted q rows (packed bf16), head-invariant: wave w owns tiles 2w, 2w+1
    short8 qx[2][2];
    #pragma unroll
    for (int t = 0; t < 2; ++t) {
        int r = (2 * w + t) * 16 + L15; if (r > TT - 1) r = TT - 1;
        const float* px = q + xbase + (long)r * HH + quad * 8;
        qx[t][0] = packx(px);
        qx[t][1] = packx(px + 32);
    }

    // hoisted K/V rows for this wave's 4 proj jobs (head-invariant)
    short8 xf[4][2];
    #pragma unroll
    for (int i = 0; i < 4; ++i) {
        const int jb = w + 10 * i;
        const int isV = jb >= 19;
        const int t = isV ? jb - 19 : jb;
        const float* X = isV ? v : k;
        int r = t * 16 + L15; if (r > TT - 1) r = TT - 1;
        const float* px = X + xbase + (long)r * HH + quad * 8;
        xf[i][0] = packx(px);
        xf[i][1] = packx(px + 32);
    }

    f32x4 y[2][4];
    #pragma unroll
    for (int sl = 0; sl < 2; ++sl)
        #pragma unroll
        for (int n = 0; n < 4; ++n) { y[sl][n][0]=0.f; y[sl][n][1]=0.f; y[sl][n][2]=0.f; y[sl][n][3]=0.f; }

    for (int h = 0; h < NHEAD; ++h) {
        __syncthreads();   // prior head's readers done; h=0: pad-init visible

        proj_kv(xf, wf, h, sK, sV, w, lane, L15, quad);

        short8 qa8[2][2];
        qa8[0][0] = qa8[0][1] = qa8[1][0] = qa8[1][1] = short8{0,0,0,0,0,0,0,0};
        qproj_reg(qx[0], wf, h, qa8[0], lane);
        qproj_reg(qx[1], wf, h, qa8[1], lane);

        __syncthreads();   // sK/sV complete

        f32x4 oT[2][4]; float ls[2] = {0.f, 0.f};
        #pragma unroll
        for (int su = 0; su < 2; ++su)
            #pragma unroll
            for (int n = 0; n < 4; ++n) { oT[su][n][0]=0.f; oT[su][n][1]=0.f; oT[su][n][2]=0.f; oT[su][n][3]=0.f; }
        attn_pass2(sK, sV, qa8, oT, ls, L15, quad);
        epilogue(wf, h, ls[0], oT[0], y[0], lane);
        epilogue(wf, h, ls[1], oT[1], y[1], lane);
    }

    store_tile(out, xbase, 2 * w + 0, y[0], L15, quad);   // tile 19 rows >=300: no store
    store_tile(out, xbase, 2 * w + 1, y[1], L15, quad);
}

// ================= Fallback (proven R2 kernel) for tiny ws =================
#define TPAD 320
#define KSTR 72
#define VSTR 328
#define WSTR 72
#define NWAVE 8
#define MAXTILE 3

__global__ __launch_bounds__(512, 1)
void mha_mfma(const float* __restrict__ q, const float* __restrict__ k,
              const float* __restrict__ v,
              const float* __restrict__ Wq, const float* __restrict__ Wk,
              const float* __restrict__ Wv, const float* __restrict__ Wo,
              float* __restrict__ out)
{
    __shared__ short sK [TPAD * KSTR];
    __shared__ short sVT[DKV * VSTR];
    __shared__ short sWq[DKV * WSTR];
    __shared__ short sWk[DKV * WSTR];
    __shared__ short sWv[DKV * WSTR];
    __shared__ short sWo[DKV * WSTR];
    __shared__ short sScrF[NWAVE][16 * KSTR];

    const int tid  = threadIdx.x;
    const int w    = tid >> 6;
    const int lane = tid & 63;
    const int L15  = lane & 15;
    const int quad = lane >> 4;

    const int blk = blockIdx.x;
    const int j = blk % NJ;
    const int b = blk / NJ;
    const long xbase = ((long)b * SS + (long)j * TT) * HH;

    for (int idx = tid; idx < 20 * KSTR; idx += 512) sK[300 * KSTR + idx] = 0;
    for (int idx = tid; idx < DKV * 32; idx += 512) {
        const int d = idx >> 5, c = 300 + (idx & 31);
        if (c < VSTR) sVT[d * VSTR + c] = 0;
    }

    int myT[MAXTILE]; int nMy = 0;
    for (int t = w; t < NQT; t += NWAVE) myT[nMy++] = t;

    f32x4 y[MAXTILE][4];
    #pragma unroll
    for (int a = 0; a < MAXTILE; ++a)
        #pragma unroll
        for (int n = 0; n < 4; ++n) { y[a][n][0]=0.f; y[a][n][1]=0.f; y[a][n][2]=0.f; y[a][n][3]=0.f; }

    for (int h = 0; h < NHEAD; ++h) {
        __syncthreads();
        for (int idx = tid; idx < 4096; idx += 512) {
            const int d = idx & 63;
            const int i = idx >> 6;
            sWq[d * WSTR + i] = f2bf(Wq[i * HDW + h * DKV + d]);
            sWk[d * WSTR + i] = f2bf(Wk[i * HDW + h * DKV + d]);
            sWv[d * WSTR + i] = f2bf(Wv[i * HDW + h * DKV + d]);
            sWo[d * WSTR + i] = f2bf(Wo[(h * DKV + i) * HH + d]);
        }
        __syncthreads();

        for (int jb = w; jb < 2 * NQT; jb += NWAVE) {
            const int   isV  = jb >= NQT;
            const int   tile = isV ? jb - NQT : jb;
            const float* X   = isV ? v : k;
            const short* sW  = isV ? sWv : sWk;
            int r = tile * 16 + L15; if (r > TT - 1) r = TT - 1;
            short8 afr[2];
            #pragma unroll
            for (int kt = 0; kt < 2; ++kt) {
                const float* px = X + xbase + (long)r * HH + kt * 32 + quad * 8;
                const float4 x0 = *(const float4*)px;
                const float4 x1 = *(const float4*)(px + 4);
                short8 a;
                a[0]=f2bf(x0.x); a[1]=f2bf(x0.y); a[2]=f2bf(x0.z); a[3]=f2bf(x0.w);
                a[4]=f2bf(x1.x); a[5]=f2bf(x1.y); a[6]=f2bf(x1.z); a[7]=f2bf(x1.w);
                afr[kt] = a;
            }
            #pragma unroll
            for (int nt = 0; nt < 4; ++nt) {
                f32x4 c; c[0]=0.f; c[1]=0.f; c[2]=0.f; c[3]=0.f;
                #pragma unroll
                for (int kt = 0; kt < 2; ++kt) {
                    const short8 bfr = *(const short8*)&sW[(nt*16 + L15) * WSTR + kt*32 + quad*8];
                    c = MFMA32(afr[kt], bfr, c);
                }
                #pragma unroll
                for (int rr = 0; rr < 4; ++rr) {
                    const int s = tile*16 + quad*4 + rr;
                    if (s < TT) {
                        const short bv = f2bf(c[rr]);
                        const int d = nt*16 + L15;
                        if (isV) sVT[d * VSTR + s] = bv;
                        else     sK [s * KSTR + d] = bv;
                    }
                }
            }
        }
        __syncthreads();

        for (int ti = 0; ti < nMy; ++ti) {
            const int tile = myT[ti];
            short8 qa[2];
            {
                int r = tile * 16 + L15; if (r > TT - 1) r = TT - 1;
                short8 afr[2];
                #pragma unroll
                for (int kt = 0; kt < 2; ++kt) {
                    const float* px = q + xbase + (long)r * HH + kt * 32 + quad * 8;
                    const float4 x0 = *(const float4*)px;
                    const float4 x1 = *(const float4*)(px + 4);
                    short8 a;
                    a[0]=f2bf(x0.x); a[1]=f2bf(x0.y); a[2]=f2bf(x0.z); a[3]=f2bf(x0.w);
                    a[4]=f2bf(x1.x); a[5]=f2bf(x1.y); a[6]=f2bf(x1.z); a[7]=f2bf(x1.w);
                    afr[kt] = a;
                }
                #pragma unroll
                for (int nt = 0; nt < 4; ++nt) {
                    f32x4 c; c[0]=0.f; c[1]=0.f; c[2]=0.f; c[3]=0.f;
                    #pragma unroll
                    for (int kt = 0; kt < 2; ++kt) {
                        const short8 bfr = *(const short8*)&sWq[(nt*16 + L15) * WSTR + kt*32 + quad*8];
                        c = MFMA32(afr[kt], bfr, c);
                    }
                    #pragma unroll
                    for (int rr = 0; rr < 4; ++rr)
                        sScrF[w][(quad*4+rr)*KSTR + nt*16 + L15] = f2bf(c[rr] * 0.125f);
                }
                LGKM_BAR();
                qa[0] = *(const short8*)&sScrF[w][L15*KSTR + quad*8];
                qa[1] = *(const short8*)&sScrF[w][L15*KSTR + 32 + quad*8];
            }

            float m[4] = {-3e38f, -3e38f, -3e38f, -3e38f};
            float l[4] = {0.f, 0.f, 0.f, 0.f};
            f32x4 o[4];
            #pragma unroll
            for (int nt = 0; nt < 4; ++nt) { o[nt][0]=0.f; o[nt][1]=0.f; o[nt][2]=0.f; o[nt][3]=0.f; }

            for (int st = 0; st < NST; ++st) {
                f32x4 s0, s1;
                s0[0]=0.f;s0[1]=0.f;s0[2]=0.f;s0[3]=0.f;
                s1[0]=0.f;s1[1]=0.f;s1[2]=0.f;s1[3]=0.f;
                #pragma unroll
                for (int kt = 0; kt < 2; ++kt) {
                    const short8 b0 = *(const short8*)&sK[(st*32      + L15) * KSTR + kt*32 + quad*8];
                    const short8 b1 = *(const short8*)&sK[(st*32 + 16 + L15) * KSTR + kt*32 + quad*8];
                    s0 = MFMA32(qa[kt], b0, s0);
                    s1 = MFMA32(qa[kt], b1, s1);
                }
                if (st == NST - 1) {
                    if (L15 >= 12) { s0[0]=-1e38f; s0[1]=-1e38f; s0[2]=-1e38f; s0[3]=-1e38f; }
                    s1[0]=-1e38f; s1[1]=-1e38f; s1[2]=-1e38f; s1[3]=-1e38f;
                }
                float corr[4];
                #pragma unroll
                for (int rr = 0; rr < 4; ++rr) {
                    float t = fmaxf(s0[rr], s1[rr]);
                    t = fmaxf(t, __shfl_xor(t, 1));
                    t = fmaxf(t, __shfl_xor(t, 2));
                    t = fmaxf(t, __shfl_xor(t, 4));
                    t = fmaxf(t, __shfl_xor(t, 8));
                    const float mn = fmaxf(m[rr], t);
                    corr[rr] = __expf(m[rr] - mn);
                    m[rr] = mn;
                    const float p0 = __expf(s0[rr] - mn);
                    const float p1 = __expf(s1[rr] - mn);
                    float rs = p0 + p1;
                    rs += __shfl_xor(rs, 1);
                    rs += __shfl_xor(rs, 2);
                    rs += __shfl_xor(rs, 4);
                    rs += __shfl_xor(rs, 8);
                    l[rr] = l[rr] * corr[rr] + rs;
                    sScrF[w][(quad*4+rr)*KSTR + L15]      = f2bf(p0);
                    sScrF[w][(quad*4+rr)*KSTR + 16 + L15] = f2bf(p1);
                }
                #pragma unroll
                for (int nt = 0; nt < 4; ++nt) {
                    o[nt][0] *= corr[0]; o[nt][1] *= corr[1];
                    o[nt][2] *= corr[2]; o[nt][3] *= corr[3];
                }
                LGKM_BAR();
                const short8 pa = *(const short8*)&sScrF[w][L15*KSTR + quad*8];
                #pragma unroll
                for (int nt = 0; nt < 4; ++nt) {
                    const short8 vb = *(const short8*)&sVT[(nt*16 + L15) * VSTR + st*32 + quad*8];
                    o[nt] = MFMA32(pa, vb, o[nt]);
                }
            }

            float linv[4];
            #pragma unroll
            for (int rr = 0; rr < 4; ++rr) linv[rr] = 1.f / l[rr];
            #pragma unroll
            for (int nt = 0; nt < 4; ++nt)
                #pragma unroll
                for (int rr = 0; rr < 4; ++rr)
                    sScrF[w][(quad*4+rr)*KSTR + nt*16 + L15] = f2bf(o[nt][rr] * linv[rr]);
            LGKM_BAR();
            const short8 oa0 = *(const short8*)&sScrF[w][L15*KSTR + quad*8];
            const short8 oa1 = *(const short8*)&sScrF[w][L15*KSTR + 32 + quad*8];
            #pragma unroll
            for (int nt = 0; nt < 4; ++nt) {
                const short8 w0 = *(const short8*)&sWo[(nt*16 + L15) * WSTR + quad*8];
                const short8 w1 = *(const short8*)&sWo[(nt*16 + L15) * WSTR + 32 + quad*8];
                y[ti][nt] = MFMA32(oa0, w0, y[ti][nt]);
                y[ti][nt] = MFMA32(oa1, w1, y[ti][nt]);
            }
        }
    }

    for (int ti = 0; ti < nMy; ++ti) {
        const int tile = myT[ti];
        #pragma unroll
        for (int nt = 0; nt < 4; ++nt)
            #pragma unroll
            for (int rr = 0; rr < 4; ++rr) {
                const int row = tile*16 + quad*4 + rr;
                if (row < TT)
                    out[xbase + (long)row * HH + nt*16 + L15] = y[ti][nt][rr];
            }
    }
}

extern "C" void kernel_launch(void* const* d_in, const int* in_sizes, int n_in,
                              void* d_out, int out_size, void* d_ws, size_t ws_size,
                              hipStream_t stream) {
    const float* q  = (const float*)d_in[0];
    const float* k  = (const float*)d_in[1];
    const float* v  = (const float*)d_in[2];
    const float* Wq = (const float*)d_in[3];
    const float* Wk = (const float*)d_in[4];
    const float* Wv = (const float*)d_in[5];
    const float* Wo = (const float*)d_in[6];
    float* out = (float*)d_out;

    if (ws_size >= WS_BYTES) {
        unsigned short* ws = (unsigned short*)d_ws;
        wfrag_kernel<<<160, 64, 0, stream>>>(Wq, Wk, Wv, Wo, ws);
        attn9<<<NB * NJ, 640, 0, stream>>>(q, k, v, ws, out);
    } else {
        mha_mfma<<<NB * NJ, 512, 0, stream>>>(q, k, v, Wq, Wk, Wv, Wo, out);
    }
}

// Round 7
// 265.502 us; speedup vs baseline: 1.1738x; 1.1738x over previous
//
#include <hip/hip_runtime.h>
#include <hip/hip_bf16.h>

// Problem constants
#define NB 16
#define SS 7500
#define HH 64
#define TT 300
#define NHEAD 4
#define DKV 64
#define NJ 25
#define HDW 256
#define NQT 19
#define NST 10       // s-tiles of 32

typedef __attribute__((ext_vector_type(8))) short short8;
typedef __attribute__((ext_vector_type(4))) short s16x4;
typedef __attribute__((ext_vector_type(4))) float f32x4;

__device__ inline short f2bf(float f) {
    union { float f; unsigned u; } x; x.f = f;
    unsigned u = x.u + 0x7FFFu + ((x.u >> 16) & 1u);
    return (short)(u >> 16);
}
__device__ inline unsigned pk2(float a, float b) {  // packed fp32x2 -> bf16x2
    __hip_bfloat162 h = __float22bfloat162_rn(make_float2(a, b));
    union { __hip_bfloat162 h; unsigned u; } c; c.h = h; return c.u;
}
#define MFMA32(a, b, c) __builtin_amdgcn_mfma_f32_16x16x32_bf16((a), (b), (c), 0, 0, 0)
#define LGKM_BAR() asm volatile("s_waitcnt lgkmcnt(0)" ::: "memory")

__device__ __forceinline__ short8 pks8(unsigned a, unsigned b, unsigned c2, unsigned d) {
    union { uint4 u; short8 s; } c; c.u.x = a; c.u.y = b; c.u.z = c2; c.u.w = d; return c.s;
}
__device__ __forceinline__ short8 cat8(s16x4 a, s16x4 b) {
    return __builtin_shufflevector(a, b, 0, 1, 2, 3, 4, 5, 6, 7);
}
__device__ __forceinline__ short8 packx(const float* px) {
    const float4 x0 = *(const float4*)px;
    const float4 x1 = *(const float4*)(px + 4);
    union { uint4 u; short8 s; } cv;
    cv.u.x = pk2(x0.x, x0.y); cv.u.y = pk2(x0.z, x0.w);
    cv.u.z = pk2(x1.x, x1.y); cv.u.w = pk2(x1.z, x1.w);
    return cv.s;
}

// ws layout (bf16 units): QKV B-frags (96 frags x 512 shorts) + Wo K=16 frags
// (64 frags x 256 shorts). 131072 bytes total.
#define WS_BYTES ((size_t)65536 * 2)
#define WOBASE 49152

// ---------------- A0: weights -> bf16 fragment arrays ----------------
__global__ void wfrag_kernel(const float* __restrict__ Wq, const float* __restrict__ Wk,
                             const float* __restrict__ Wv, const float* __restrict__ Wo,
                             unsigned short* __restrict__ ws) {
    const int f = blockIdx.x;
    const int lane = threadIdx.x;
    const int L15 = lane & 15, quad = lane >> 4;
    if (f < 96) {
        const int matid = f >> 5, nt = (f & 31) >> 1, kt = f & 1;
        const float* W = matid == 0 ? Wq : (matid == 1 ? Wk : Wv);
        const int n = nt * 16 + L15;
        unsigned short* dst = ws + f * 512 + lane * 8;
        #pragma unroll
        for (int i = 0; i < 8; ++i)
            dst[i] = (unsigned short)f2bf(W[(kt * 32 + quad * 8 + i) * HDW + n]);
    } else {
        const int g = f - 96, nt = g & 3, kt = g >> 2;
        const int n = nt * 16 + L15;
        unsigned short* dst = ws + WOBASE + g * 256 + lane * 4;
        #pragma unroll
        for (int i = 0; i < 4; ++i)
            dst[i] = (unsigned short)f2bf(Wo[(kt * 16 + quad * 4 + i) * HH + n]);
    }
}

// ---------------- fully fused: proj + attention + out-proj ----------------
// 640 threads (10 waves), SINGLE-buffered sK/sV (79360 B) => LDS permits
// 2 blocks/CU (155KB <= 160KB): all 400 blocks co-resident in ONE grid round,
// and the sibling block fills barrier/dependency stalls.
// __launch_bounds__(640, 2): the ONLY spill-free configuration in the
// empirical map -- (512,4) and (640,4) both forced a 64-reg cap and spilled
// accumulators (WRITE_SIZE 517MB / 127MB); (640,2)/(640,3) compile to 84 VGPR
// with zero scratch. At 84 VGPR the HW pool admits 5 waves/SIMD (5x88<=512)
// = 20 waves/CU = two 10-wave blocks. Spill tripwire: WRITE_SIZE ~30MB.
// KEY IDENTITY: MFMA32(cat(a1,a2), cat(b1,b2)) == MFMA16(a1,b1)+MFMA16(a2,b2)
// => all K=16 fragment pairs are concatenated in-lane and fed to K=32 MFMA.
// K/V/Q input rows are head-invariant: loaded+packed ONCE into registers.
// sK[row][64]: K'^T rows; 16-short blocks XOR-swizzled by (row&3).
// sV[d][320]: V'^T; blocks (st*2 + quad>>1) XOR (d&3).

__device__ __forceinline__ void proj_kv(const short8 xf[4][2],
                                        const unsigned short* __restrict__ wf, int hp,
                                        unsigned short* __restrict__ dK, unsigned short* __restrict__ dV,
                                        int w, int lane, int L15, int quad) {
    // 40 job slots over 10 waves (4 each); jb>=38 are naturally store-masked dummies
    #pragma unroll
    for (int i = 0; i < 4; ++i) {
        const int jb = w + 10 * i;
        const int isV = jb >= 19;
        const int t = isV ? jb - 19 : jb;
        const unsigned short* mb = wf + (isV ? 2 : 1) * 16384;
        if (!isV) {
            const int s = t * 16 + L15;   // unclamped store row
            #pragma unroll
            for (int ntl = 0; ntl < 4; ++ntl) {
                const short8 b0 = *(const short8*)&mb[((hp * 4 + ntl) * 2 + 0) * 512 + lane * 8];
                const short8 b1 = *(const short8*)&mb[((hp * 4 + ntl) * 2 + 1) * 512 + lane * 8];
                f32x4 c = {0.f, 0.f, 0.f, 0.f};
                c = MFMA32(b0, xf[i][0], c);   // A=W => C = K'^T[d'][s], s on L15
                c = MFMA32(b1, xf[i][1], c);
                if (s < TT) {
                    uint2 pkd; pkd.x = pk2(c[0], c[1]); pkd.y = pk2(c[2], c[3]);
                    const int pp = ntl >> 1, oo = ntl & 1;
                    const int blk = ((pp << 1) | (quad >> 1)) ^ (s & 3);
                    *(uint2*)&dK[s * 64 + (blk << 4) + ((quad & 1) << 3) + (oo << 2)] = pkd;
                }
            }
        } else {
            const int sb = t * 16 + quad * 4;
            const int stv = t >> 1, rhv = t & 1;
            #pragma unroll
            for (int ntl = 0; ntl < 4; ++ntl) {
                const short8 b0 = *(const short8*)&mb[((hp * 4 + ntl) * 2 + 0) * 512 + lane * 8];
                const short8 b1 = *(const short8*)&mb[((hp * 4 + ntl) * 2 + 1) * 512 + lane * 8];
                f32x4 c = {0.f, 0.f, 0.f, 0.f};
                c = MFMA32(xf[i][0], b0, c);   // A=x => C = V'[s][d], d on L15
                c = MFMA32(xf[i][1], b1, c);
                if (sb < TT) {
                    const int d = ntl * 16 + L15;
                    uint2 pkd; pkd.x = pk2(c[0], c[1]); pkd.y = pk2(c[2], c[3]);
                    const int blk = ((stv << 1) | (quad >> 1)) ^ (d & 3);
                    *(uint2*)&dV[d * 320 + (blk << 4) + ((quad & 1) << 3) + (rhv << 2)] = pkd;
                }
            }
        }
    }
}

// Q' projection -> two concatenated K=32 B-frags (qa8[0] pairs with sK's k0
// chunk, qa8[1] with k1); scale 1/8 folded.
__device__ __forceinline__ void qproj_reg(const short8 qx[2],
                                          const unsigned short* __restrict__ wf,
                                          int h, short8* qa8, int lane) {
    #pragma unroll
    for (int p = 0; p < 2; ++p) {
        unsigned pkv[4];
        #pragma unroll
        for (int hf = 0; hf < 2; ++hf) {
            const int ntl = 2 * p + hf;
            const short8 b0 = *(const short8*)&wf[((h * 4 + ntl) * 2 + 0) * 512 + lane * 8];
            const short8 b1 = *(const short8*)&wf[((h * 4 + ntl) * 2 + 1) * 512 + lane * 8];
            f32x4 c = {0.f, 0.f, 0.f, 0.f};
            c = MFMA32(b0, qx[0], c);   // A=W (swapped) => C = Q'^T[d'][q], q on L15
            c = MFMA32(b1, qx[1], c);
            pkv[2 * hf + 0] = pk2(c[0] * 0.125f, c[1] * 0.125f);
            pkv[2 * hf + 1] = pk2(c[2] * 0.125f, c[3] * 0.125f);
        }
        qa8[p] = pks8(pkv[0], pkv[1], pkv[2], pkv[3]);
    }
}

__device__ __forceinline__ void attn_pass2(const unsigned short* __restrict__ sK,
                                           const unsigned short* __restrict__ sV,
                                           const short8 qa8[2][2], f32x4 oT[2][4],
                                           float* __restrict__ lsum,
                                           int L15, int quad) {
    #pragma unroll 2
    for (int st = 0; st < NST; ++st) {
        unsigned ptw[2][4];
        #pragma unroll
        for (int rh = 0; rh < 2; ++rh) {
            int row = st * 32 + rh * 16 + L15; if (row > TT - 1) row = TT - 1;
            const int rb = row * 64 + ((quad & 1) << 3);
            const short8 k0 = *(const short8*)&sK[rb + ((((quad >> 1) | 0) ^ (row & 3)) << 4)];
            const short8 k1 = *(const short8*)&sK[rb + ((((quad >> 1) | 2) ^ (row & 3)) << 4)];
            #pragma unroll
            for (int su = 0; su < 2; ++su) {
                f32x4 c = {0.f, 0.f, 0.f, 0.f};
                c = MFMA32(k0, qa8[su][0], c);
                c = MFMA32(k1, qa8[su][1], c);
                if (st == NST - 1) {      // mask s >= 300 (s = 288+rh*16+quad*4+rr)
                    if (rh == 1 || quad == 3) {
                        c[0] = -1e38f; c[1] = -1e38f; c[2] = -1e38f; c[3] = -1e38f;
                    }
                }
                // fixed-max softmax p=exp(s-16); exact after 1/l
                const float p0 = __expf(c[0] - 16.f);
                const float p1 = __expf(c[1] - 16.f);
                const float p2 = __expf(c[2] - 16.f);
                const float p3 = __expf(c[3] - 16.f);
                lsum[su] += (p0 + p1) + (p2 + p3);
                ptw[su][2 * rh + 0] = pk2(p0, p1);
                ptw[su][2 * rh + 1] = pk2(p2, p3);
            }
        }
        const short8 pa0 = pks8(ptw[0][0], ptw[0][1], ptw[0][2], ptw[0][3]);
        const short8 pa1 = pks8(ptw[1][0], ptw[1][1], ptw[1][2], ptw[1][3]);
        #pragma unroll
        for (int nt = 0; nt < 4; ++nt) {
            const int d = nt * 16 + L15;
            const int blk = ((st << 1) | (quad >> 1)) ^ (d & 3);
            const short8 vp = *(const short8*)&sV[d * 320 + (blk << 4) + ((quad & 1) << 3)];
            oT[0][nt] = MFMA32(vp, pa0, oT[0][nt]);
            oT[1][nt] = MFMA32(vp, pa1, oT[1][nt]);
        }
    }
}

__device__ __forceinline__ void epilogue(const unsigned short* __restrict__ wf, int h,
                                         float lsum, const f32x4* oT, f32x4* y, int lane) {
    lsum += __shfl_xor(lsum, 16);
    lsum += __shfl_xor(lsum, 32);
    const float linv = 1.f / lsum;
    short8 oa8[2];   // in-lane A-frag packs, kc pairs concatenated to K=32
    #pragma unroll
    for (int p = 0; p < 2; ++p)
        oa8[p] = pks8(pk2(oT[2 * p][0] * linv, oT[2 * p][1] * linv),
                      pk2(oT[2 * p][2] * linv, oT[2 * p][3] * linv),
                      pk2(oT[2 * p + 1][0] * linv, oT[2 * p + 1][1] * linv),
                      pk2(oT[2 * p + 1][2] * linv, oT[2 * p + 1][3] * linv));
    #pragma unroll
    for (int nc = 0; nc < 4; ++nc) {
        #pragma unroll
        for (int p = 0; p < 2; ++p) {
            const s16x4 w0 = *(const s16x4*)&wf[WOBASE + (((h * 4 + 2 * p + 0) * 4 + nc) << 8) + (lane << 2)];
            const s16x4 w1 = *(const s16x4*)&wf[WOBASE + (((h * 4 + 2 * p + 1) * 4 + nc) << 8) + (lane << 2)];
            y[nc] = MFMA32(oa8[p], cat8(w0, w1), y[nc]);
        }
    }
}

__device__ __forceinline__ void store_tile(float* __restrict__ out, long xbase, int tile,
                                           const f32x4* y, int L15, int quad) {
    #pragma unroll
    for (int nc = 0; nc < 4; ++nc)
        #pragma unroll
        for (int rr = 0; rr < 4; ++rr) {
            const int row = tile * 16 + quad * 4 + rr;
            if (row < TT)
                out[xbase + (long)row * HH + nc * 16 + L15] = y[nc][rr];
        }
}

__global__ __launch_bounds__(640, 2)
void attn10(const float* __restrict__ q, const float* __restrict__ k,
            const float* __restrict__ v, const unsigned short* __restrict__ wf,
            float* __restrict__ out)
{
    __shared__ __align__(16) unsigned short sK[19200];   // 38400 B
    __shared__ __align__(16) unsigned short sV[20480];   // 40960 B

    const int tid = threadIdx.x;
    const int w = tid >> 6, lane = tid & 63;
    const int L15 = lane & 15, quad = lane >> 4;
    const int bj = blockIdx.x;
    const int b = bj / NJ, j = bj % NJ;
    const long xbase = ((long)b * SS + (long)j * TT) * HH;

    // zero V pad (logical s 288..319 of st=9; valid parts rewritten each head)
    for (int i = tid; i < 2048; i += 640) {
        const int d = i >> 5, off = 288 + (i & 31);
        const int blk = (off >> 4) ^ (d & 3);
        sV[d * 320 + (blk << 4) + (off & 15)] = 0;
    }

    // hoisted q rows (packed bf16), head-invariant: wave w owns tiles 2w, 2w+1
    short8 qx[2][2];
    #pragma unroll
    for (int t = 0; t < 2; ++t) {
        int r = (2 * w + t) * 16 + L15; if (r > TT - 1) r = TT - 1;
        const float* px = q + xbase + (long)r * HH + quad * 8;
        qx[t][0] = packx(px);
        qx[t][1] = packx(px + 32);
    }

    // hoisted K/V rows for this wave's 4 proj jobs (head-invariant)
    short8 xf[4][2];
    #pragma unroll
    for (int i = 0; i < 4; ++i) {
        const int jb = w + 10 * i;
        const int isV = jb >= 19;
        const int t = isV ? jb - 19 : jb;
        const float* X = isV ? v : k;
        int r = t * 16 + L15; if (r > TT - 1) r = TT - 1;
        const float* px = X + xbase + (long)r * HH + quad * 8;
        xf[i][0] = packx(px);
        xf[i][1] = packx(px + 32);
    }

    f32x4 y[2][4];
    #pragma unroll
    for (int sl = 0; sl < 2; ++sl)
        #pragma unroll
        for (int n = 0; n < 4; ++n) { y[sl][n][0]=0.f; y[sl][n][1]=0.f; y[sl][n][2]=0.f; y[sl][n][3]=0.f; }

    for (int h = 0; h < NHEAD; ++h) {
        __syncthreads();   // prior head's readers done; h=0: pad-init visible

        proj_kv(xf, wf, h, sK, sV, w, lane, L15, quad);

        short8 qa8[2][2];
        qproj_reg(qx[0], wf, h, qa8[0], lane);
        qproj_reg(qx[1], wf, h, qa8[1], lane);

        __syncthreads();   // sK/sV complete

        f32x4 oT[2][4]; float ls[2] = {0.f, 0.f};
        #pragma unroll
        for (int su = 0; su < 2; ++su)
            #pragma unroll
            for (int n = 0; n < 4; ++n) { oT[su][n][0]=0.f; oT[su][n][1]=0.f; oT[su][n][2]=0.f; oT[su][n][3]=0.f; }
        attn_pass2(sK, sV, qa8, oT, ls, L15, quad);
        epilogue(wf, h, ls[0], oT[0], y[0], lane);
        epilogue(wf, h, ls[1], oT[1], y[1], lane);
    }

    store_tile(out, xbase, 2 * w + 0, y[0], L15, quad);   // tile 19 rows >=300: no store
    store_tile(out, xbase, 2 * w + 1, y[1], L15, quad);
}

// ================= Fallback (proven R2 kernel) for tiny ws =================
#define TPAD 320
#define KSTR 72
#define VSTR 328
#define WSTR 72
#define NWAVE 8
#define MAXTILE 3

__global__ __launch_bounds__(512, 1)
void mha_mfma(const float* __restrict__ q, const float* __restrict__ k,
              const float* __restrict__ v,
              const float* __restrict__ Wq, const float* __restrict__ Wk,
              const float* __restrict__ Wv, const float* __restrict__ Wo,
              float* __restrict__ out)
{
    __shared__ short sK [TPAD * KSTR];
    __shared__ short sVT[DKV * VSTR];
    __shared__ short sWq[DKV * WSTR];
    __shared__ short sWk[DKV * WSTR];
    __shared__ short sWv[DKV * WSTR];
    __shared__ short sWo[DKV * WSTR];
    __shared__ short sScrF[NWAVE][16 * KSTR];

    const int tid  = threadIdx.x;
    const int w    = tid >> 6;
    const int lane = tid & 63;
    const int L15  = lane & 15;
    const int quad = lane >> 4;

    const int blk = blockIdx.x;
    const int j = blk % NJ;
    const int b = blk / NJ;
    const long xbase = ((long)b * SS + (long)j * TT) * HH;

    for (int idx = tid; idx < 20 * KSTR; idx += 512) sK[300 * KSTR + idx] = 0;
    for (int idx = tid; idx < DKV * 32; idx += 512) {
        const int d = idx >> 5, c = 300 + (idx & 31);
        if (c < VSTR) sVT[d * VSTR + c] = 0;
    }

    int myT[MAXTILE]; int nMy = 0;
    for (int t = w; t < NQT; t += NWAVE) myT[nMy++] = t;

    f32x4 y[MAXTILE][4];
    #pragma unroll
    for (int a = 0; a < MAXTILE; ++a)
        #pragma unroll
        for (int n = 0; n < 4; ++n) { y[a][n][0]=0.f; y[a][n][1]=0.f; y[a][n][2]=0.f; y[a][n][3]=0.f; }

    for (int h = 0; h < NHEAD; ++h) {
        __syncthreads();
        for (int idx = tid; idx < 4096; idx += 512) {
            const int d = idx & 63;
            const int i = idx >> 6;
            sWq[d * WSTR + i] = f2bf(Wq[i * HDW + h * DKV + d]);
            sWk[d * WSTR + i] = f2bf(Wk[i * HDW + h * DKV + d]);
            sWv[d * WSTR + i] = f2bf(Wv[i * HDW + h * DKV + d]);
            sWo[d * WSTR + i] = f2bf(Wo[(h * DKV + i) * HH + d]);
        }
        __syncthreads();

        for (int jb = w; jb < 2 * NQT; jb += NWAVE) {
            const int   isV  = jb >= NQT;
            const int   tile = isV ? jb - NQT : jb;
            const float* X   = isV ? v : k;
            const short* sW  = isV ? sWv : sWk;
            int r = tile * 16 + L15; if (r > TT - 1) r = TT - 1;
            short8 afr[2];
            #pragma unroll
            for (int kt = 0; kt < 2; ++kt) {
                const float* px = X + xbase + (long)r * HH + kt * 32 + quad * 8;
                const float4 x0 = *(const float4*)px;
                const float4 x1 = *(const float4*)(px + 4);
                short8 a;
                a[0]=f2bf(x0.x); a[1]=f2bf(x0.y); a[2]=f2bf(x0.z); a[3]=f2bf(x0.w);
                a[4]=f2bf(x1.x); a[5]=f2bf(x1.y); a[6]=f2bf(x1.z); a[7]=f2bf(x1.w);
                afr[kt] = a;
            }
            #pragma unroll
            for (int nt = 0; nt < 4; ++nt) {
                f32x4 c; c[0]=0.f; c[1]=0.f; c[2]=0.f; c[3]=0.f;
                #pragma unroll
                for (int kt = 0; kt < 2; ++kt) {
                    const short8 bfr = *(const short8*)&sW[(nt*16 + L15) * WSTR + kt*32 + quad*8];
                    c = MFMA32(afr[kt], bfr, c);
                }
                #pragma unroll
                for (int rr = 0; rr < 4; ++rr) {
                    const int s = tile*16 + quad*4 + rr;
                    if (s < TT) {
                        const short bv = f2bf(c[rr]);
                        const int d = nt*16 + L15;
                        if (isV) sVT[d * VSTR + s] = bv;
                        else     sK [s * KSTR + d] = bv;
                    }
                }
            }
        }
        __syncthreads();

        for (int ti = 0; ti < nMy; ++ti) {
            const int tile = myT[ti];
            short8 qa[2];
            {
                int r = tile * 16 + L15; if (r > TT - 1) r = TT - 1;
                short8 afr[2];
                #pragma unroll
                for (int kt = 0; kt < 2; ++kt) {
                    const float* px = q + xbase + (long)r * HH + kt * 32 + quad * 8;
                    const float4 x0 = *(const float4*)px;
                    const float4 x1 = *(const float4*)(px + 4);
                    short8 a;
                    a[0]=f2bf(x0.x); a[1]=f2bf(x0.y); a[2]=f2bf(x0.z); a[3]=f2bf(x0.w);
                    a[4]=f2bf(x1.x); a[5]=f2bf(x1.y); a[6]=f2bf(x1.z); a[7]=f2bf(x1.w);
                    afr[kt] = a;
                }
                #pragma unroll
                for (int nt = 0; nt < 4; ++nt) {
                    f32x4 c; c[0]=0.f; c[1]=0.f; c[2]=0.f; c[3]=0.f;
                    #pragma unroll
                    for (int kt = 0; kt < 2; ++kt) {
                        const short8 bfr = *(const short8*)&sWq[(nt*16 + L15) * WSTR + kt*32 + quad*8];
                        c = MFMA32(afr[kt], bfr, c);
                    }
                    #pragma unroll
                    for (int rr = 0; rr < 4; ++rr)
                        sScrF[w][(quad*4+rr)*KSTR + nt*16 + L15] = f2bf(c[rr] * 0.125f);
                }
                LGKM_BAR();
                qa[0] = *(const short8*)&sScrF[w][L15*KSTR + quad*8];
                qa[1] = *(const short8*)&sScrF[w][L15*KSTR + 32 + quad*8];
            }

            float m[4] = {-3e38f, -3e38f, -3e38f, -3e38f};
            float l[4] = {0.f, 0.f, 0.f, 0.f};
            f32x4 o[4];
            #pragma unroll
            for (int nt = 0; nt < 4; ++nt) { o[nt][0]=0.f; o[nt][1]=0.f; o[nt][2]=0.f; o[nt][3]=0.f; }

            for (int st = 0; st < NST; ++st) {
                f32x4 s0, s1;
                s0[0]=0.f;s0[1]=0.f;s0[2]=0.f;s0[3]=0.f;
                s1[0]=0.f;s1[1]=0.f;s1[2]=0.f;s1[3]=0.f;
                #pragma unroll
                for (int kt = 0; kt < 2; ++kt) {
                    const short8 b0 = *(const short8*)&sK[(st*32      + L15) * KSTR + kt*32 + quad*8];
                    const short8 b1 = *(const short8*)&sK[(st*32 + 16 + L15) * KSTR + kt*32 + quad*8];
                    s0 = MFMA32(qa[kt], b0, s0);
                    s1 = MFMA32(qa[kt], b1, s1);
                }
                if (st == NST - 1) {
                    if (L15 >= 12) { s0[0]=-1e38f; s0[1]=-1e38f; s0[2]=-1e38f; s0[3]=-1e38f; }
                    s1[0]=-1e38f; s1[1]=-1e38f; s1[2]=-1e38f; s1[3]=-1e38f;
                }
                float corr[4];
                #pragma unroll
                for (int rr = 0; rr < 4; ++rr) {
                    float t = fmaxf(s0[rr], s1[rr]);
                    t = fmaxf(t, __shfl_xor(t, 1));
                    t = fmaxf(t, __shfl_xor(t, 2));
                    t = fmaxf(t, __shfl_xor(t, 4));
                    t = fmaxf(t, __shfl_xor(t, 8));
                    const float mn = fmaxf(m[rr], t);
                    corr[rr] = __expf(m[rr] - mn);
                    m[rr] = mn;
                    const float p0 = __expf(s0[rr] - mn);
                    const float p1 = __expf(s1[rr] - mn);
                    float rs = p0 + p1;
                    rs += __shfl_xor(rs, 1);
                    rs += __shfl_xor(rs, 2);
                    rs += __shfl_xor(rs, 4);
                    rs += __shfl_xor(rs, 8);
                    l[rr] = l[rr] * corr[rr] + rs;
                    sScrF[w][(quad*4+rr)*KSTR + L15]      = f2bf(p0);
                    sScrF[w][(quad*4+rr)*KSTR + 16 + L15] = f2bf(p1);
                }
                #pragma unroll
                for (int nt = 0; nt < 4; ++nt) {
                    o[nt][0] *= corr[0]; o[nt][1] *= corr[1];
                    o[nt][2] *= corr[2]; o[nt][3] *= corr[3];
                }
                LGKM_BAR();
                const short8 pa = *(const short8*)&sScrF[w][L15*KSTR + quad*8];
                #pragma unroll
                for (int nt = 0; nt < 4; ++nt) {
                    const short8 vb = *(const short8*)&sVT[(nt*16 + L15) * VSTR + st*32 + quad*8];
                    o[nt] = MFMA32(pa, vb, o[nt]);
                }
            }

            float linv[4];
            #pragma unroll
            for (int rr = 0; rr < 4; ++rr) linv[rr] = 1.f / l[rr];
            #pragma unroll
            for (int nt = 0; nt < 4; ++nt)
                #pragma unroll
                for (int rr = 0; rr < 4; ++rr)
                    sScrF[w][(quad*4+rr)*KSTR + nt*16 + L15] = f2bf(o[nt][rr] * linv[rr]);
            LGKM_BAR();
            const short8 oa0 = *(const short8*)&sScrF[w][L15*KSTR + quad*8];
            const short8 oa1 = *(const short8*)&sScrF[w][L15*KSTR + 32 + quad*8];
            #pragma unroll
            for (int nt = 0; nt < 4; ++nt) {
                const short8 w0 = *(const short8*)&sWo[(nt*16 + L15) * WSTR + quad*8];
                const short8 w1 = *(const short8*)&sWo[(nt*16 + L15) * WSTR + 32 + quad*8];
                y[ti][nt] = MFMA32(oa0, w0, y[ti][nt]);
                y[ti][nt] = MFMA32(oa1, w1, y[ti][nt]);
            }
        }
    }

    for (int ti = 0; ti < nMy; ++ti) {
        const int tile = myT[ti];
        #pragma unroll
        for (int nt = 0; nt < 4; ++nt)
            #pragma unroll
            for (int rr = 0; rr < 4; ++rr) {
                const int row = tile*16 + quad*4 + rr;
                if (row < TT)
                    out[xbase + (long)row * HH + nt*16 + L15] = y[ti][nt][rr];
            }
    }
}

extern "C" void kernel_launch(void* const* d_in, const int* in_sizes, int n_in,
                              void* d_out, int out_size, void* d_ws, size_t ws_size,
                              hipStream_t stream) {
    const float* q  = (const float*)d_in[0];
    const float* k  = (const float*)d_in[1];
    const float* v  = (const float*)d_in[2];
    const float* Wq = (const float*)d_in[3];
    const float* Wk = (const float*)d_in[4];
    const float* Wv = (const float*)d_in[5];
    const float* Wo = (const float*)d_in[6];
    float* out = (float*)d_out;

    if (ws_size >= WS_BYTES) {
        unsigned short* ws = (unsigned short*)d_ws;
        wfrag_kernel<<<160, 64, 0, stream>>>(Wq, Wk, Wv, Wo, ws);
        attn10<<<NB * NJ, 640, 0, stream>>>(q, k, v, ws, out);
    } else {
        mha_mfma<<<NB * NJ, 512, 0, stream>>>(q, k, v, Wq, Wk, Wv, Wo, out);
    }
}

// Round 8
// 225.921 us; speedup vs baseline: 1.3795x; 1.1752x over previous
//
#include <hip/hip_runtime.h>
#include <hip/hip_bf16.h>

// Problem constants
#define NB 16
#define SS 7500
#define HH 64
#define TT 300
#define NHEAD 4
#define DKV 64
#define NJ 25
#define HDW 256
#define NQT 19
#define NST 10       // s-tiles of 32

typedef __attribute__((ext_vector_type(8))) short short8;
typedef __attribute__((ext_vector_type(4))) short s16x4;
typedef __attribute__((ext_vector_type(4))) float f32x4;

__device__ inline short f2bf(float f) {
    union { float f; unsigned u; } x; x.f = f;
    unsigned u = x.u + 0x7FFFu + ((x.u >> 16) & 1u);
    return (short)(u >> 16);
}
__device__ inline unsigned pk2(float a, float b) {  // packed fp32x2 -> bf16x2
    __hip_bfloat162 h = __float22bfloat162_rn(make_float2(a, b));
    union { __hip_bfloat162 h; unsigned u; } c; c.h = h; return c.u;
}
#define MFMA32(a, b, c) __builtin_amdgcn_mfma_f32_16x16x32_bf16((a), (b), (c), 0, 0, 0)
#define LGKM_BAR() asm volatile("s_waitcnt lgkmcnt(0)" ::: "memory")

__device__ __forceinline__ short8 pks8(unsigned a, unsigned b, unsigned c2, unsigned d) {
    union { uint4 u; short8 s; } c; c.u.x = a; c.u.y = b; c.u.z = c2; c.u.w = d; return c.s;
}
__device__ __forceinline__ short8 cat8(s16x4 a, s16x4 b) {
    return __builtin_shufflevector(a, b, 0, 1, 2, 3, 4, 5, 6, 7);
}
__device__ __forceinline__ short8 packx(const float* px) {
    const float4 x0 = *(const float4*)px;
    const float4 x1 = *(const float4*)(px + 4);
    union { uint4 u; short8 s; } cv;
    cv.u.x = pk2(x0.x, x0.y); cv.u.y = pk2(x0.z, x0.w);
    cv.u.z = pk2(x1.x, x1.y); cv.u.w = pk2(x1.z, x1.w);
    return cv.s;
}

// ===================== ALGEBRAIC REFACTOR (R8) =====================
// scores = (qWq)(kWk)^T = q · M_h · k^T with M_h = Wq_h Wk_h^T / 8  (64x64)
// out_h  = P (vWv) Wo_h = P · v · N_h with N_h = Wv_h Wo_h          (64x64)
// => K'/V' projections DELETED. LDS holds RAW k and RAW v^T, staged ONCE
// (head-invariant). Head loop is barrier-free pure compute.
// ws layout (bf16 units): M-frags 32x512 shorts (idx = h*8+ntl*2+kt, columns
// sigma-permuted so the qm repack is in-lane natural-labeled), then N-frags
// 64x256 shorts at WOBASE (idx = h*16+kc*4+nc, Wo-frag-style K=16).
#define WS_BYTES ((size_t)65536 * 2)
#define WOBASE 16384

// ---------------- A0: weight-product fragment arrays ----------------
__global__ void wfrag_kernel(const float* __restrict__ Wq, const float* __restrict__ Wk,
                             const float* __restrict__ Wv, const float* __restrict__ Wo,
                             unsigned short* __restrict__ ws) {
    const int f = blockIdx.x;
    const int lane = threadIdx.x;
    const int L15 = lane & 15, quad = lane >> 4;
    if (f < 32) {
        // M_h frag: h=f>>3, ntl=(f>>1)&3, kt=f&1. k-slot = qrow = kt*32+quad*8+i.
        // col position c holds M[.][sigma(c)]: sigma swaps hf-bit with quad-bits so
        // the qm C-output packs in-lane to NATURAL k-labels (j = p*32+quad*8+i).
        const int h = f >> 3, ntl = (f >> 1) & 3, kt = f & 1;
        const int c = ntl * 16 + L15;
        const int j = (c & 32) | ((c & 12) << 1) | ((c & 16) >> 2) | (c & 3);
        const float* wkp = Wk + j * HDW + h * 64;
        float acc[8] = {0.f, 0.f, 0.f, 0.f, 0.f, 0.f, 0.f, 0.f};
        for (int dd = 0; dd < 64; ++dd) {
            const float kv = wkp[dd];
            #pragma unroll
            for (int i = 0; i < 8; ++i)
                acc[i] += Wq[(kt * 32 + quad * 8 + i) * HDW + h * 64 + dd] * kv;
        }
        unsigned short* dst = ws + f * 512 + lane * 8;
        #pragma unroll
        for (int i = 0; i < 8; ++i)
            dst[i] = (unsigned short)f2bf(acc[i] * 0.125f);   // fold 1/sqrt(dk)
    } else {
        // N_h frag (K=16, Wo-style): g=f-32: h=g>>4, kc=(g>>2)&3, nc=g&3.
        // k = model dim i = kc*16+quad*4+ii; col n = nc*16+L15.
        const int g = f - 32, h = g >> 4, kc = (g >> 2) & 3, nc = g & 3;
        const int n = nc * 16 + L15;
        float acc[4] = {0.f, 0.f, 0.f, 0.f};
        for (int dd = 0; dd < 64; ++dd) {
            const float wo = Wo[(h * 64 + dd) * HH + n];
            #pragma unroll
            for (int i = 0; i < 4; ++i)
                acc[i] += Wv[(kc * 16 + quad * 4 + i) * HDW + h * 64 + dd] * wo;
        }
        unsigned short* dst = ws + WOBASE + g * 256 + lane * 4;
        #pragma unroll
        for (int i = 0; i < 4; ++i)
            dst[i] = (unsigned short)f2bf(acc[i]);
    }
}

// ---------------- fused kernel: stage-once + barrier-free head loop --------
// LDS: sK raw k rows [300][64] bf16, 8x 16B blocks/row XOR-swizzled by (row&7)
//      => all reads/writes 2-way (free). 38400 B.
//      sV raw v^T [64][stride 328]: content at paired positions
//      pos(s) = (s&~31) + ((s>>2)&3)*8 + ((s>>4)&1)*4 + (s&3)  (matches the
//      P-fragment slot labeling); stride 328 staggers 16B phase per d row
//      => vp reads 2-way (free). 41984 B. Total 80384 B => 2 blocks/CU.
// Barriers: 2 at start (pad-init, staging); NONE in the head loop.

__device__ __forceinline__ void qproj_reg(const short8 qx[2],
                                          const unsigned short* __restrict__ wf,
                                          int h, short8* qa8, int lane) {
    #pragma unroll
    for (int p = 0; p < 2; ++p) {
        unsigned pkv[4];
        #pragma unroll
        for (int hf = 0; hf < 2; ++hf) {
            const int ntl = 2 * p + hf;
            const short8 b0 = *(const short8*)&wf[((h * 4 + ntl) * 2 + 0) * 512 + lane * 8];
            const short8 b1 = *(const short8*)&wf[((h * 4 + ntl) * 2 + 1) * 512 + lane * 8];
            f32x4 c = {0.f, 0.f, 0.f, 0.f};
            c = MFMA32(b0, qx[0], c);   // A=M(sigma) => C rows = permuted j, col=q
            c = MFMA32(b1, qx[1], c);
            pkv[2 * hf + 0] = pk2(c[0], c[1]);   // scale folded into M
            pkv[2 * hf + 1] = pk2(c[2], c[3]);
        }
        qa8[p] = pks8(pkv[0], pkv[1], pkv[2], pkv[3]);  // natural j = p*32+quad*8+i
    }
}

__device__ __forceinline__ void attn_pass2(const unsigned short* __restrict__ sK,
                                           const unsigned short* __restrict__ sV,
                                           const short8 qa8[2][2], f32x4 oT[2][4],
                                           float* __restrict__ lsum,
                                           int L15, int quad) {
    #pragma unroll 2
    for (int st = 0; st < NST; ++st) {
        unsigned ptw[2][4];
        #pragma unroll
        for (int rh = 0; rh < 2; ++rh) {
            int row = st * 32 + rh * 16 + L15; if (row > TT - 1) row = TT - 1;
            const int r7 = row & 7;
            const short8 k0 = *(const short8*)&sK[row * 64 + ((quad ^ r7) << 3)];
            const short8 k1 = *(const short8*)&sK[row * 64 + (((4 + quad) ^ r7) << 3)];
            #pragma unroll
            for (int su = 0; su < 2; ++su) {
                f32x4 c = {0.f, 0.f, 0.f, 0.f};
                c = MFMA32(k0, qa8[su][0], c);
                c = MFMA32(k1, qa8[su][1], c);
                if (st == NST - 1) {      // mask s >= 300 (s = 288+rh*16+quad*4+rr)
                    if (rh == 1 || quad == 3) {
                        c[0] = -1e38f; c[1] = -1e38f; c[2] = -1e38f; c[3] = -1e38f;
                    }
                }
                // fixed-max softmax p=exp(s-16); exact after 1/l
                const float p0 = __expf(c[0] - 16.f);
                const float p1 = __expf(c[1] - 16.f);
                const float p2 = __expf(c[2] - 16.f);
                const float p3 = __expf(c[3] - 16.f);
                lsum[su] += (p0 + p1) + (p2 + p3);
                ptw[su][2 * rh + 0] = pk2(p0, p1);
                ptw[su][2 * rh + 1] = pk2(p2, p3);
            }
        }
        const short8 pa0 = pks8(ptw[0][0], ptw[0][1], ptw[0][2], ptw[0][3]);
        const short8 pa1 = pks8(ptw[1][0], ptw[1][1], ptw[1][2], ptw[1][3]);
        #pragma unroll
        for (int nt = 0; nt < 4; ++nt) {
            const int d = nt * 16 + L15;
            const short8 vp = *(const short8*)&sV[d * 328 + st * 32 + quad * 8];
            oT[0][nt] = MFMA32(vp, pa0, oT[0][nt]);
            oT[1][nt] = MFMA32(vp, pa1, oT[1][nt]);
        }
    }
}

__device__ __forceinline__ void epilogue(const unsigned short* __restrict__ wf, int h,
                                         float lsum, const f32x4* oT, f32x4* y, int lane) {
    lsum += __shfl_xor(lsum, 16);
    lsum += __shfl_xor(lsum, 32);
    const float linv = 1.f / lsum;
    short8 oa8[2];   // in-lane A-frag packs of O (model dims), K=16 pairs -> K=32
    #pragma unroll
    for (int p = 0; p < 2; ++p)
        oa8[p] = pks8(pk2(oT[2 * p][0] * linv, oT[2 * p][1] * linv),
                      pk2(oT[2 * p][2] * linv, oT[2 * p][3] * linv),
                      pk2(oT[2 * p + 1][0] * linv, oT[2 * p + 1][1] * linv),
                      pk2(oT[2 * p + 1][2] * linv, oT[2 * p + 1][3] * linv));
    #pragma unroll
    for (int nc = 0; nc < 4; ++nc) {
        #pragma unroll
        for (int p = 0; p < 2; ++p) {
            const s16x4 w0 = *(const s16x4*)&wf[WOBASE + (((h * 4 + 2 * p + 0) * 4 + nc) << 8) + (lane << 2)];
            const s16x4 w1 = *(const s16x4*)&wf[WOBASE + (((h * 4 + 2 * p + 1) * 4 + nc) << 8) + (lane << 2)];
            y[nc] = MFMA32(oa8[p], cat8(w0, w1), y[nc]);
        }
    }
}

__device__ __forceinline__ void store_tile(float* __restrict__ out, long xbase, int tile,
                                           const f32x4* y, int L15, int quad) {
    #pragma unroll
    for (int nc = 0; nc < 4; ++nc)
        #pragma unroll
        for (int rr = 0; rr < 4; ++rr) {
            const int row = tile * 16 + quad * 4 + rr;
            if (row < TT)
                out[xbase + (long)row * HH + nc * 16 + L15] = y[nc][rr];
        }
}

__global__ __launch_bounds__(640, 2)
void attn11(const float* __restrict__ q, const float* __restrict__ k,
            const float* __restrict__ v, const unsigned short* __restrict__ wf,
            float* __restrict__ out)
{
    __shared__ __align__(16) unsigned short sK[19200];     // 300x64, 38400 B
    __shared__ __align__(16) unsigned short sV[64 * 328];  // 41984 B

    const int tid = threadIdx.x;
    const int w = tid >> 6, lane = tid & 63;
    const int L15 = lane & 15, quad = lane >> 4;
    const int bj = blockIdx.x;
    const int b = bj / NJ, j = bj % NJ;
    const long xbase = ((long)b * SS + (long)j * TT) * HH;

    // 1) zero sV positions [288..328) of every d row (covers pad; valid
    //    s=288..299 slots are rewritten by staging AFTER the barrier)
    for (int i = tid; i < 2560; i += 640) {
        const int d = i / 40, p = 288 + (i % 40);
        sV[d * 328 + p] = 0;
    }

    // hoisted q rows (packed bf16), head-invariant: wave w owns tiles 2w, 2w+1
    short8 qx[2][2];
    #pragma unroll
    for (int t = 0; t < 2; ++t) {
        int r = (2 * w + t) * 16 + L15; if (r > TT - 1) r = TT - 1;
        const float* px = q + xbase + (long)r * HH + quad * 8;
        qx[t][0] = packx(px);
        qx[t][1] = packx(px + 32);
    }

    f32x4 y[2][4];
    #pragma unroll
    for (int sl = 0; sl < 2; ++sl)
        #pragma unroll
        for (int n = 0; n < 4; ++n) { y[sl][n][0]=0.f; y[sl][n][1]=0.f; y[sl][n][2]=0.f; y[sl][n][3]=0.f; }

    __syncthreads();   // pad-init visible before staging writes

    // 2) one-time staging of RAW k rows and RAW v^T: 38 jobs over 10 waves
    for (int ji = 0; ji < 4; ++ji) {
        const int jb = w + 10 * ji;
        if (jb >= 38) break;                 // wave-uniform
        const int isV = jb >= 19;
        const int t = isV ? jb - 19 : jb;
        const int s = t * 16 + L15;
        const int r = s > TT - 1 ? TT - 1 : s;
        const float* X = isV ? v : k;
        const float* px = X + xbase + (long)r * HH + quad * 8;
        const short8 xf0 = packx(px);
        const short8 xf1 = packx(px + 32);
        if (s < TT) {
            if (!isV) {
                const int p0 = (quad ^ (s & 7)) << 3;
                const int p1 = ((4 + quad) ^ (s & 7)) << 3;
                *(short8*)&sK[s * 64 + p0] = xf0;
                *(short8*)&sK[s * 64 + p1] = xf1;
            } else {
                // scalar transpose into paired positions (once per kernel)
                const int pos = (s & ~31) + ((s >> 2) & 3) * 8 + ((s >> 4) & 1) * 4 + (s & 3);
                const unsigned short* a0 = (const unsigned short*)&xf0;
                const unsigned short* a1 = (const unsigned short*)&xf1;
                #pragma unroll
                for (int jj = 0; jj < 8; ++jj) {
                    sV[(quad * 8 + jj) * 328 + pos]        = a0[jj];
                    sV[(quad * 8 + jj + 32) * 328 + pos]   = a1[jj];
                }
            }
        }
    }
    __syncthreads();   // staging complete; head loop is barrier-free

    // 3) head loop: pure compute (qm + attention + epilogue)
    for (int h = 0; h < NHEAD; ++h) {
        short8 qa8[2][2];
        qproj_reg(qx[0], wf, h, qa8[0], lane);
        qproj_reg(qx[1], wf, h, qa8[1], lane);

        f32x4 oT[2][4]; float ls[2] = {0.f, 0.f};
        #pragma unroll
        for (int su = 0; su < 2; ++su)
            #pragma unroll
            for (int n = 0; n < 4; ++n) { oT[su][n][0]=0.f; oT[su][n][1]=0.f; oT[su][n][2]=0.f; oT[su][n][3]=0.f; }
        attn_pass2(sK, sV, qa8, oT, ls, L15, quad);
        epilogue(wf, h, ls[0], oT[0], y[0], lane);
        epilogue(wf, h, ls[1], oT[1], y[1], lane);
    }

    store_tile(out, xbase, 2 * w + 0, y[0], L15, quad);   // tile 19 rows >=300: no store
    store_tile(out, xbase, 2 * w + 1, y[1], L15, quad);
}

// ================= Fallback (proven R2 kernel) for tiny ws =================
#define TPAD 320
#define KSTR 72
#define VSTR 328
#define WSTR 72
#define NWAVE 8
#define MAXTILE 3

__global__ __launch_bounds__(512, 1)
void mha_mfma(const float* __restrict__ q, const float* __restrict__ k,
              const float* __restrict__ v,
              const float* __restrict__ Wq, const float* __restrict__ Wk,
              const float* __restrict__ Wv, const float* __restrict__ Wo,
              float* __restrict__ out)
{
    __shared__ short sK [TPAD * KSTR];
    __shared__ short sVT[DKV * VSTR];
    __shared__ short sWq[DKV * WSTR];
    __shared__ short sWk[DKV * WSTR];
    __shared__ short sWv[DKV * WSTR];
    __shared__ short sWo[DKV * WSTR];
    __shared__ short sScrF[NWAVE][16 * KSTR];

    const int tid  = threadIdx.x;
    const int w    = tid >> 6;
    const int lane = tid & 63;
    const int L15  = lane & 15;
    const int quad = lane >> 4;

    const int blk = blockIdx.x;
    const int j = blk % NJ;
    const int b = blk / NJ;
    const long xbase = ((long)b * SS + (long)j * TT) * HH;

    for (int idx = tid; idx < 20 * KSTR; idx += 512) sK[300 * KSTR + idx] = 0;
    for (int idx = tid; idx < DKV * 32; idx += 512) {
        const int d = idx >> 5, c = 300 + (idx & 31);
        if (c < VSTR) sVT[d * VSTR + c] = 0;
    }

    int myT[MAXTILE]; int nMy = 0;
    for (int t = w; t < NQT; t += NWAVE) myT[nMy++] = t;

    f32x4 y[MAXTILE][4];
    #pragma unroll
    for (int a = 0; a < MAXTILE; ++a)
        #pragma unroll
        for (int n = 0; n < 4; ++n) { y[a][n][0]=0.f; y[a][n][1]=0.f; y[a][n][2]=0.f; y[a][n][3]=0.f; }

    for (int h = 0; h < NHEAD; ++h) {
        __syncthreads();
        for (int idx = tid; idx < 4096; idx += 512) {
            const int d = idx & 63;
            const int i = idx >> 6;
            sWq[d * WSTR + i] = f2bf(Wq[i * HDW + h * DKV + d]);
            sWk[d * WSTR + i] = f2bf(Wk[i * HDW + h * DKV + d]);
            sWv[d * WSTR + i] = f2bf(Wv[i * HDW + h * DKV + d]);
            sWo[d * WSTR + i] = f2bf(Wo[(h * DKV + i) * HH + d]);
        }
        __syncthreads();

        for (int jb = w; jb < 2 * NQT; jb += NWAVE) {
            const int   isV  = jb >= NQT;
            const int   tile = isV ? jb - NQT : jb;
            const float* X   = isV ? v : k;
            const short* sW  = isV ? sWv : sWk;
            int r = tile * 16 + L15; if (r > TT - 1) r = TT - 1;
            short8 afr[2];
            #pragma unroll
            for (int kt = 0; kt < 2; ++kt) {
                const float* px = X + xbase + (long)r * HH + kt * 32 + quad * 8;
                const float4 x0 = *(const float4*)px;
                const float4 x1 = *(const float4*)(px + 4);
                short8 a;
                a[0]=f2bf(x0.x); a[1]=f2bf(x0.y); a[2]=f2bf(x0.z); a[3]=f2bf(x0.w);
                a[4]=f2bf(x1.x); a[5]=f2bf(x1.y); a[6]=f2bf(x1.z); a[7]=f2bf(x1.w);
                afr[kt] = a;
            }
            #pragma unroll
            for (int nt = 0; nt < 4; ++nt) {
                f32x4 c; c[0]=0.f; c[1]=0.f; c[2]=0.f; c[3]=0.f;
                #pragma unroll
                for (int kt = 0; kt < 2; ++kt) {
                    const short8 bfr = *(const short8*)&sW[(nt*16 + L15) * WSTR + kt*32 + quad*8];
                    c = MFMA32(afr[kt], bfr, c);
                }
                #pragma unroll
                for (int rr = 0; rr < 4; ++rr) {
                    const int s = tile*16 + quad*4 + rr;
                    if (s < TT) {
                        const short bv = f2bf(c[rr]);
                        const int d = nt*16 + L15;
                        if (isV) sVT[d * VSTR + s] = bv;
                        else     sK [s * KSTR + d] = bv;
                    }
                }
            }
        }
        __syncthreads();

        for (int ti = 0; ti < nMy; ++ti) {
            const int tile = myT[ti];
            short8 qa[2];
            {
                int r = tile * 16 + L15; if (r > TT - 1) r = TT - 1;
                short8 afr[2];
                #pragma unroll
                for (int kt = 0; kt < 2; ++kt) {
                    const float* px = q + xbase + (long)r * HH + kt * 32 + quad * 8;
                    const float4 x0 = *(const float4*)px;
                    const float4 x1 = *(const float4*)(px + 4);
                    short8 a;
                    a[0]=f2bf(x0.x); a[1]=f2bf(x0.y); a[2]=f2bf(x0.z); a[3]=f2bf(x0.w);
                    a[4]=f2bf(x1.x); a[5]=f2bf(x1.y); a[6]=f2bf(x1.z); a[7]=f2bf(x1.w);
                    afr[kt] = a;
                }
                #pragma unroll
                for (int nt = 0; nt < 4; ++nt) {
                    f32x4 c; c[0]=0.f; c[1]=0.f; c[2]=0.f; c[3]=0.f;
                    #pragma unroll
                    for (int kt = 0; kt < 2; ++kt) {
                        const short8 bfr = *(const short8*)&sWq[(nt*16 + L15) * WSTR + kt*32 + quad*8];
                        c = MFMA32(afr[kt], bfr, c);
                    }
                    #pragma unroll
                    for (int rr = 0; rr < 4; ++rr)
                        sScrF[w][(quad*4+rr)*KSTR + nt*16 + L15] = f2bf(c[rr] * 0.125f);
                }
                LGKM_BAR();
                qa[0] = *(const short8*)&sScrF[w][L15*KSTR + quad*8];
                qa[1] = *(const short8*)&sScrF[w][L15*KSTR + 32 + quad*8];
            }

            float m[4] = {-3e38f, -3e38f, -3e38f, -3e38f};
            float l[4] = {0.f, 0.f, 0.f, 0.f};
            f32x4 o[4];
            #pragma unroll
            for (int nt = 0; nt < 4; ++nt) { o[nt][0]=0.f; o[nt][1]=0.f; o[nt][2]=0.f; o[nt][3]=0.f; }

            for (int st = 0; st < NST; ++st) {
                f32x4 s0, s1;
                s0[0]=0.f;s0[1]=0.f;s0[2]=0.f;s0[3]=0.f;
                s1[0]=0.f;s1[1]=0.f;s1[2]=0.f;s1[3]=0.f;
                #pragma unroll
                for (int kt = 0; kt < 2; ++kt) {
                    const short8 b0 = *(const short8*)&sK[(st*32      + L15) * KSTR + kt*32 + quad*8];
                    const short8 b1 = *(const short8*)&sK[(st*32 + 16 + L15) * KSTR + kt*32 + quad*8];
                    s0 = MFMA32(qa[kt], b0, s0);
                    s1 = MFMA32(qa[kt], b1, s1);
                }
                if (st == NST - 1) {
                    if (L15 >= 12) { s0[0]=-1e38f; s0[1]=-1e38f; s0[2]=-1e38f; s0[3]=-1e38f; }
                    s1[0]=-1e38f; s1[1]=-1e38f; s1[2]=-1e38f; s1[3]=-1e38f;
                }
                float corr[4];
                #pragma unroll
                for (int rr = 0; rr < 4; ++rr) {
                    float t = fmaxf(s0[rr], s1[rr]);
                    t = fmaxf(t, __shfl_xor(t, 1));
                    t = fmaxf(t, __shfl_xor(t, 2));
                    t = fmaxf(t, __shfl_xor(t, 4));
                    t = fmaxf(t, __shfl_xor(t, 8));
                    const float mn = fmaxf(m[rr], t);
                    corr[rr] = __expf(m[rr] - mn);
                    m[rr] = mn;
                    const float p0 = __expf(s0[rr] - mn);
                    const float p1 = __expf(s1[rr] - mn);
                    float rs = p0 + p1;
                    rs += __shfl_xor(rs, 1);
                    rs += __shfl_xor(rs, 2);
                    rs += __shfl_xor(rs, 4);
                    rs += __shfl_xor(rs, 8);
                    l[rr] = l[rr] * corr[rr] + rs;
                    sScrF[w][(quad*4+rr)*KSTR + L15]      = f2bf(p0);
                    sScrF[w][(quad*4+rr)*KSTR + 16 + L15] = f2bf(p1);
                }
                #pragma unroll
                for (int nt = 0; nt < 4; ++nt) {
                    o[nt][0] *= corr[0]; o[nt][1] *= corr[1];
                    o[nt][2] *= corr[2]; o[nt][3] *= corr[3];
                }
                LGKM_BAR();
                const short8 pa = *(const short8*)&sScrF[w][L15*KSTR + quad*8];
                #pragma unroll
                for (int nt = 0; nt < 4; ++nt) {
                    const short8 vb = *(const short8*)&sVT[(nt*16 + L15) * VSTR + st*32 + quad*8];
                    o[nt] = MFMA32(pa, vb, o[nt]);
                }
            }

            float linv[4];
            #pragma unroll
            for (int rr = 0; rr < 4; ++rr) linv[rr] = 1.f / l[rr];
            #pragma unroll
            for (int nt = 0; nt < 4; ++nt)
                #pragma unroll
                for (int rr = 0; rr < 4; ++rr)
                    sScrF[w][(quad*4+rr)*KSTR + nt*16 + L15] = f2bf(o[nt][rr] * linv[rr]);
            LGKM_BAR();
            const short8 oa0 = *(const short8*)&sScrF[w][L15*KSTR + quad*8];
            const short8 oa1 = *(const short8*)&sScrF[w][L15*KSTR + 32 + quad*8];
            #pragma unroll
            for (int nt = 0; nt < 4; ++nt) {
                const short8 w0 = *(const short8*)&sWo[(nt*16 + L15) * WSTR + quad*8];
                const short8 w1 = *(const short8*)&sWo[(nt*16 + L15) * WSTR + 32 + quad*8];
                y[ti][nt] = MFMA32(oa0, w0, y[ti][nt]);
                y[ti][nt] = MFMA32(oa1, w1, y[ti][nt]);
            }
        }
    }

    for (int ti = 0; ti < nMy; ++ti) {
        const int tile = myT[ti];
        #pragma unroll
        for (int nt = 0; nt < 4; ++nt)
            #pragma unroll
            for (int rr = 0; rr < 4; ++rr) {
                const int row = tile*16 + quad*4 + rr;
                if (row < TT)
                    out[xbase + (long)row * HH + nt*16 + L15] = y[ti][nt][rr];
            }
    }
}

extern "C" void kernel_launch(void* const* d_in, const int* in_sizes, int n_in,
                              void* d_out, int out_size, void* d_ws, size_t ws_size,
                              hipStream_t stream) {
    const float* q  = (const float*)d_in[0];
    const float* k  = (const float*)d_in[1];
    const float* v  = (const float*)d_in[2];
    const float* Wq = (const float*)d_in[3];
    const float* Wk = (const float*)d_in[4];
    const float* Wv = (const float*)d_in[5];
    const float* Wo = (const float*)d_in[6];
    float* out = (float*)d_out;

    if (ws_size >= WS_BYTES) {
        unsigned short* ws = (unsigned short*)d_ws;
        wfrag_kernel<<<96, 64, 0, stream>>>(Wq, Wk, Wv, Wo, ws);
        attn11<<<NB * NJ, 640, 0, stream>>>(q, k, v, ws, out);
    } else {
        mha_mfma<<<NB * NJ, 512, 0, stream>>>(q, k, v, Wq, Wk, Wv, Wo, out);
    }
}

// Round 10
// 205.493 us; speedup vs baseline: 1.5166x; 1.0994x over previous
//
#include <hip/hip_runtime.h>
#include <hip/hip_bf16.h>

// Problem constants
#define NB 16
#define SS 7500
#define HH 64
#define TT 300
#define NHEAD 4
#define DKV 64
#define NJ 25
#define HDW 256
#define NQT 19
#define NST 10       // s-tiles of 32

typedef __attribute__((ext_vector_type(8))) short short8;
typedef __attribute__((ext_vector_type(4))) short s16x4;
typedef __attribute__((ext_vector_type(4))) float f32x4;

__device__ inline short f2bf(float f) {
    union { float f; unsigned u; } x; x.f = f;
    unsigned u = x.u + 0x7FFFu + ((x.u >> 16) & 1u);
    return (short)(u >> 16);
}
__device__ inline unsigned pk2(float a, float b) {  // packed fp32x2 -> bf16x2
    __hip_bfloat162 h = __float22bfloat162_rn(make_float2(a, b));
    union { __hip_bfloat162 h; unsigned u; } c; c.h = h; return c.u;
}
#define MFMA32(a, b, c) __builtin_amdgcn_mfma_f32_16x16x32_bf16((a), (b), (c), 0, 0, 0)
#define LGKM_BAR() asm volatile("s_waitcnt lgkmcnt(0)" ::: "memory")
// raw v_exp_f32 (2^x). NOTE: `__exp2f` is NOT a HIP intrinsic (collides with
// glibc math.h macro -> R9 compile failure); the amdgcn builtin is the way.
#define EXP2(x) __builtin_amdgcn_exp2f(x)

__device__ __forceinline__ short8 pks8(unsigned a, unsigned b, unsigned c2, unsigned d) {
    union { uint4 u; short8 s; } c; c.u.x = a; c.u.y = b; c.u.z = c2; c.u.w = d; return c.s;
}
__device__ __forceinline__ short8 cat8(s16x4 a, s16x4 b) {
    return __builtin_shufflevector(a, b, 0, 1, 2, 3, 4, 5, 6, 7);
}
__device__ __forceinline__ short8 packx(const float* px) {
    const float4 x0 = *(const float4*)px;
    const float4 x1 = *(const float4*)(px + 4);
    union { uint4 u; short8 s; } cv;
    cv.u.x = pk2(x0.x, x0.y); cv.u.y = pk2(x0.z, x0.w);
    cv.u.z = pk2(x1.x, x1.y); cv.u.w = pk2(x1.z, x1.w);
    return cv.s;
}

// ===================== ALGEBRAIC FORM (R8) =====================
// scores*log2e = q · M_h · k^T with M_h = Wq_h Wk_h^T * (log2e/8)  (64x64)
// out_h  = P · v · N_h with N_h = Wv_h Wo_h                        (64x64)
// K'/V' projections deleted; LDS holds RAW k and RAW v^T staged ONCE.
// log2e folded into M => softmax uses raw v_exp_f32 (2^x), no mul.
#define WS_BYTES ((size_t)65536 * 2)
#define WOBASE 16384
#define EXP2_SHIFT 23.083121f   // 16 * log2(e)

// ---------------- A0: weight-product fragment arrays ----------------
__global__ void wfrag_kernel(const float* __restrict__ Wq, const float* __restrict__ Wk,
                             const float* __restrict__ Wv, const float* __restrict__ Wo,
                             unsigned short* __restrict__ ws) {
    const int f = blockIdx.x;
    const int lane = threadIdx.x;
    const int L15 = lane & 15, quad = lane >> 4;
    if (f < 32) {
        // M_h frag: h=f>>3, ntl=(f>>1)&3, kt=f&1. k-slot = qrow = kt*32+quad*8+i.
        // col position c holds M[.][sigma(c)]: sigma swaps hf-bit with quad-bits so
        // the qm C-output packs in-lane to NATURAL k-labels (j = p*32+quad*8+i).
        const int h = f >> 3, ntl = (f >> 1) & 3, kt = f & 1;
        const int c = ntl * 16 + L15;
        const int j = (c & 32) | ((c & 12) << 1) | ((c & 16) >> 2) | (c & 3);
        const float* wkp = Wk + j * HDW + h * 64;
        float acc[8] = {0.f, 0.f, 0.f, 0.f, 0.f, 0.f, 0.f, 0.f};
        for (int dd = 0; dd < 64; ++dd) {
            const float kv = wkp[dd];
            #pragma unroll
            for (int i = 0; i < 8; ++i)
                acc[i] += Wq[(kt * 32 + quad * 8 + i) * HDW + h * 64 + dd] * kv;
        }
        unsigned short* dst = ws + f * 512 + lane * 8;
        #pragma unroll
        for (int i = 0; i < 8; ++i)
            dst[i] = (unsigned short)f2bf(acc[i] * 0.18033688f);   // (1/8)*log2(e)
    } else {
        // N_h frag (K=16, Wo-style): g=f-32: h=g>>4, kc=(g>>2)&3, nc=g&3.
        const int g = f - 32, h = g >> 4, kc = (g >> 2) & 3, nc = g & 3;
        const int n = nc * 16 + L15;
        float acc[4] = {0.f, 0.f, 0.f, 0.f};
        for (int dd = 0; dd < 64; ++dd) {
            const float wo = Wo[(h * 64 + dd) * HH + n];
            #pragma unroll
            for (int i = 0; i < 4; ++i)
                acc[i] += Wv[(kc * 16 + quad * 4 + i) * HDW + h * 64 + dd] * wo;
        }
        unsigned short* dst = ws + WOBASE + g * 256 + lane * 4;
        #pragma unroll
        for (int i = 0; i < 4; ++i)
            dst[i] = (unsigned short)f2bf(acc[i]);
    }
}

// ---------------- fused kernel: 8-wave blocks, 2 blocks/CU -----------------
// OCCUPANCY FIX (R9/R10): VGPR=84 rounds to the 128-reg HW granule => 4
// waves/SIMD = 16 waves/CU. A 640-thread (10-wave) block can therefore NEVER
// have a sibling -- every prior round ran 1 block/CU and 400 blocks as 2
// serialized grid rounds. 512-thread (8-wave) blocks make 2 blocks = 16
// waves/CU fit EXACTLY: one grid round, sibling block hides latency.
// launch_bounds(512,2) = the empirically spill-free flavor ((512,4)/(640,4)
// forced a 64-reg cap and spilled: R1/R6).
// Waves 0..7 own tiles 2w,2w+1 (0..15); tiles 16..18 = su=1 tail on waves 0..2
// after the main loop (barrier-free; main-loop registers dead => low peak).
// LDS: sK[300][64] raw k, XOR-swizzle (row&7); sV[64][328] raw v^T at paired
// positions. 80384 B total => 2 blocks/CU.

__device__ __forceinline__ void qproj_reg(const short8 qx[2],
                                          const unsigned short* __restrict__ wf,
                                          int h, short8* qa8, int lane) {
    #pragma unroll
    for (int p = 0; p < 2; ++p) {
        unsigned pkv[4];
        #pragma unroll
        for (int hf = 0; hf < 2; ++hf) {
            const int ntl = 2 * p + hf;
            const short8 b0 = *(const short8*)&wf[((h * 4 + ntl) * 2 + 0) * 512 + lane * 8];
            const short8 b1 = *(const short8*)&wf[((h * 4 + ntl) * 2 + 1) * 512 + lane * 8];
            f32x4 c = {0.f, 0.f, 0.f, 0.f};
            c = MFMA32(b0, qx[0], c);   // A=M(sigma) => C rows = permuted j, col=q
            c = MFMA32(b1, qx[1], c);
            pkv[2 * hf + 0] = pk2(c[0], c[1]);   // scale+log2e folded into M
            pkv[2 * hf + 1] = pk2(c[2], c[3]);
        }
        qa8[p] = pks8(pkv[0], pkv[1], pkv[2], pkv[3]);  // natural j = p*32+quad*8+i
    }
}

template <int NSUB>
__device__ __forceinline__ void attn_pass(const unsigned short* __restrict__ sK,
                                          const unsigned short* __restrict__ sV,
                                          const short8 qa8[][2], f32x4 oT[][4],
                                          float* __restrict__ lsum,
                                          int L15, int quad) {
    #pragma unroll 2
    for (int st = 0; st < NST; ++st) {
        unsigned ptw[NSUB][4];
        #pragma unroll
        for (int rh = 0; rh < 2; ++rh) {
            int row = st * 32 + rh * 16 + L15; if (row > TT - 1) row = TT - 1;
            const int r7 = row & 7;
            const short8 k0 = *(const short8*)&sK[row * 64 + ((quad ^ r7) << 3)];
            const short8 k1 = *(const short8*)&sK[row * 64 + (((4 + quad) ^ r7) << 3)];
            #pragma unroll
            for (int su = 0; su < NSUB; ++su) {
                f32x4 c = {0.f, 0.f, 0.f, 0.f};
                c = MFMA32(k0, qa8[su][0], c);
                c = MFMA32(k1, qa8[su][1], c);
                if (st == NST - 1) {      // mask s >= 300 (s = 288+rh*16+quad*4+rr)
                    if (rh == 1 || quad == 3) {
                        c[0] = -1e38f; c[1] = -1e38f; c[2] = -1e38f; c[3] = -1e38f;
                    }
                }
                // fixed-max softmax p=2^(c-16*log2e); exact after 1/l
                const float p0 = EXP2(c[0] - EXP2_SHIFT);
                const float p1 = EXP2(c[1] - EXP2_SHIFT);
                const float p2 = EXP2(c[2] - EXP2_SHIFT);
                const float p3 = EXP2(c[3] - EXP2_SHIFT);
                lsum[su] += (p0 + p1) + (p2 + p3);
                ptw[su][2 * rh + 0] = pk2(p0, p1);
                ptw[su][2 * rh + 1] = pk2(p2, p3);
            }
        }
        short8 pa[NSUB];
        #pragma unroll
        for (int su = 0; su < NSUB; ++su)
            pa[su] = pks8(ptw[su][0], ptw[su][1], ptw[su][2], ptw[su][3]);
        #pragma unroll
        for (int nt = 0; nt < 4; ++nt) {
            const int d = nt * 16 + L15;
            const short8 vp = *(const short8*)&sV[d * 328 + st * 32 + quad * 8];
            #pragma unroll
            for (int su = 0; su < NSUB; ++su)
                oT[su][nt] = MFMA32(vp, pa[su], oT[su][nt]);
        }
    }
}

__device__ __forceinline__ void epilogue(const unsigned short* __restrict__ wf, int h,
                                         float lsum, const f32x4* oT, f32x4* y, int lane) {
    lsum += __shfl_xor(lsum, 16);
    lsum += __shfl_xor(lsum, 32);
    const float linv = 1.f / lsum;
    short8 oa8[2];   // in-lane A-frag packs of O (model dims), K=16 pairs -> K=32
    #pragma unroll
    for (int p = 0; p < 2; ++p)
        oa8[p] = pks8(pk2(oT[2 * p][0] * linv, oT[2 * p][1] * linv),
                      pk2(oT[2 * p][2] * linv, oT[2 * p][3] * linv),
                      pk2(oT[2 * p + 1][0] * linv, oT[2 * p + 1][1] * linv),
                      pk2(oT[2 * p + 1][2] * linv, oT[2 * p + 1][3] * linv));
    #pragma unroll
    for (int nc = 0; nc < 4; ++nc) {
        #pragma unroll
        for (int p = 0; p < 2; ++p) {
            const s16x4 w0 = *(const s16x4*)&wf[WOBASE + (((h * 4 + 2 * p + 0) * 4 + nc) << 8) + (lane << 2)];
            const s16x4 w1 = *(const s16x4*)&wf[WOBASE + (((h * 4 + 2 * p + 1) * 4 + nc) << 8) + (lane << 2)];
            y[nc] = MFMA32(oa8[p], cat8(w0, w1), y[nc]);
        }
    }
}

__device__ __forceinline__ void store_tile(float* __restrict__ out, long xbase, int tile,
                                           const f32x4* y, int L15, int quad) {
    #pragma unroll
    for (int nc = 0; nc < 4; ++nc)
        #pragma unroll
        for (int rr = 0; rr < 4; ++rr) {
            const int row = tile * 16 + quad * 4 + rr;
            if (row < TT)
                out[xbase + (long)row * HH + nc * 16 + L15] = y[nc][rr];
        }
}

__global__ __launch_bounds__(512, 2)
void attn13(const float* __restrict__ q, const float* __restrict__ k,
            const float* __restrict__ v, const unsigned short* __restrict__ wf,
            float* __restrict__ out)
{
    __shared__ __align__(16) unsigned short sK[19200];     // 300x64, 38400 B
    __shared__ __align__(16) unsigned short sV[64 * 328];  // 41984 B

    const int tid = threadIdx.x;
    const int w = tid >> 6, lane = tid & 63;
    const int L15 = lane & 15, quad = lane >> 4;
    const int bj = blockIdx.x;
    const int b = bj / NJ, j = bj % NJ;
    const long xbase = ((long)b * SS + (long)j * TT) * HH;

    // 1) zero sV positions [288..328) of every d row (covers pad; valid
    //    s=288..299 slots are rewritten by staging AFTER the barrier)
    for (int i = tid; i < 2560; i += 512) {
        const int d = i / 40, p = 288 + (i % 40);
        sV[d * 328 + p] = 0;
    }

    // hoisted q rows (packed bf16): wave w owns tiles 2w, 2w+1 (rows <= 255)
    short8 qx[2][2];
    #pragma unroll
    for (int t = 0; t < 2; ++t) {
        const int r = (2 * w + t) * 16 + L15;
        const float* px = q + xbase + (long)r * HH + quad * 8;
        qx[t][0] = packx(px);
        qx[t][1] = packx(px + 32);
    }

    f32x4 y[2][4];
    #pragma unroll
    for (int sl = 0; sl < 2; ++sl)
        #pragma unroll
        for (int n = 0; n < 4; ++n) { y[sl][n][0]=0.f; y[sl][n][1]=0.f; y[sl][n][2]=0.f; y[sl][n][3]=0.f; }

    __syncthreads();   // pad-init visible before staging writes

    // 2) one-time staging of RAW k rows and RAW v^T: 38 jobs over 8 waves
    for (int ji = 0; ji < 5; ++ji) {
        const int jb = w + 8 * ji;
        if (jb >= 38) break;                 // wave-uniform
        const int isV = jb >= 19;
        const int t = isV ? jb - 19 : jb;
        const int s = t * 16 + L15;
        const int r = s > TT - 1 ? TT - 1 : s;
        const float* X = isV ? v : k;
        const float* px = X + xbase + (long)r * HH + quad * 8;
        const short8 xf0 = packx(px);
        const short8 xf1 = packx(px + 32);
        if (s < TT) {
            if (!isV) {
                const int p0 = (quad ^ (s & 7)) << 3;
                const int p1 = ((4 + quad) ^ (s & 7)) << 3;
                *(short8*)&sK[s * 64 + p0] = xf0;
                *(short8*)&sK[s * 64 + p1] = xf1;
            } else {
                // scalar transpose into paired positions (once per kernel)
                const int pos = (s & ~31) + ((s >> 2) & 3) * 8 + ((s >> 4) & 1) * 4 + (s & 3);
                const unsigned short* a0 = (const unsigned short*)&xf0;
                const unsigned short* a1 = (const unsigned short*)&xf1;
                #pragma unroll
                for (int jj = 0; jj < 8; ++jj) {
                    sV[(quad * 8 + jj) * 328 + pos]        = a0[jj];
                    sV[(quad * 8 + jj + 32) * 328 + pos]   = a1[jj];
                }
            }
        }
    }
    __syncthreads();   // staging complete; rest of kernel is barrier-free

    // 3) main head loop: tiles 2w, 2w+1
    for (int h = 0; h < NHEAD; ++h) {
        short8 qa8[2][2];
        qproj_reg(qx[0], wf, h, qa8[0], lane);
        qproj_reg(qx[1], wf, h, qa8[1], lane);

        f32x4 oT[2][4]; float ls[2] = {0.f, 0.f};
        #pragma unroll
        for (int su = 0; su < 2; ++su)
            #pragma unroll
            for (int n = 0; n < 4; ++n) { oT[su][n][0]=0.f; oT[su][n][1]=0.f; oT[su][n][2]=0.f; oT[su][n][3]=0.f; }
        attn_pass<2>(sK, sV, qa8, oT, ls, L15, quad);
        epilogue(wf, h, ls[0], oT[0], y[0], lane);
        epilogue(wf, h, ls[1], oT[1], y[1], lane);
    }
    store_tile(out, xbase, 2 * w + 0, y[0], L15, quad);
    store_tile(out, xbase, 2 * w + 1, y[1], L15, quad);

    // 4) tail: waves 0..2 handle tiles 16..18 (su=1); main registers dead here
    if (w < 3) {
        const int t3 = 16 + w;
        short8 qx3[2];
        {
            int r = t3 * 16 + L15; if (r > TT - 1) r = TT - 1;
            const float* px = q + xbase + (long)r * HH + quad * 8;
            qx3[0] = packx(px);
            qx3[1] = packx(px + 32);
        }
        f32x4 y3[4];
        #pragma unroll
        for (int n = 0; n < 4; ++n) { y3[n][0]=0.f; y3[n][1]=0.f; y3[n][2]=0.f; y3[n][3]=0.f; }
        for (int h = 0; h < NHEAD; ++h) {
            short8 qa3[1][2];
            qproj_reg(qx3, wf, h, qa3[0], lane);
            f32x4 o3[1][4]; float ls3[1] = {0.f};
            #pragma unroll
            for (int n = 0; n < 4; ++n) { o3[0][n][0]=0.f; o3[0][n][1]=0.f; o3[0][n][2]=0.f; o3[0][n][3]=0.f; }
            attn_pass<1>(sK, sV, qa3, o3, ls3, L15, quad);
            epilogue(wf, h, ls3[0], o3[0], y3, lane);
        }
        store_tile(out, xbase, t3, y3, L15, quad);
    }
}

// ================= Fallback (proven R2 kernel) for tiny ws =================
#define TPAD 320
#define KSTR 72
#define VSTR 328
#define WSTR 72
#define NWAVE 8
#define MAXTILE 3

__global__ __launch_bounds__(512, 1)
void mha_mfma(const float* __restrict__ q, const float* __restrict__ k,
              const float* __restrict__ v,
              const float* __restrict__ Wq, const float* __restrict__ Wk,
              const float* __restrict__ Wv, const float* __restrict__ Wo,
              float* __restrict__ out)
{
    __shared__ short sK [TPAD * KSTR];
    __shared__ short sVT[DKV * VSTR];
    __shared__ short sWq[DKV * WSTR];
    __shared__ short sWk[DKV * WSTR];
    __shared__ short sWv[DKV * WSTR];
    __shared__ short sWo[DKV * WSTR];
    __shared__ short sScrF[NWAVE][16 * KSTR];

    const int tid  = threadIdx.x;
    const int w    = tid >> 6;
    const int lane = tid & 63;
    const int L15  = lane & 15;
    const int quad = lane >> 4;

    const int blk = blockIdx.x;
    const int j = blk % NJ;
    const int b = blk / NJ;
    const long xbase = ((long)b * SS + (long)j * TT) * HH;

    for (int idx = tid; idx < 20 * KSTR; idx += 512) sK[300 * KSTR + idx] = 0;
    for (int idx = tid; idx < DKV * 32; idx += 512) {
        const int d = idx >> 5, c = 300 + (idx & 31);
        if (c < VSTR) sVT[d * VSTR + c] = 0;
    }

    int myT[MAXTILE]; int nMy = 0;
    for (int t = w; t < NQT; t += NWAVE) myT[nMy++] = t;

    f32x4 y[MAXTILE][4];
    #pragma unroll
    for (int a = 0; a < MAXTILE; ++a)
        #pragma unroll
        for (int n = 0; n < 4; ++n) { y[a][n][0]=0.f; y[a][n][1]=0.f; y[a][n][2]=0.f; y[a][n][3]=0.f; }

    for (int h = 0; h < NHEAD; ++h) {
        __syncthreads();
        for (int idx = tid; idx < 4096; idx += 512) {
            const int d = idx & 63;
            const int i = idx >> 6;
            sWq[d * WSTR + i] = f2bf(Wq[i * HDW + h * DKV + d]);
            sWk[d * WSTR + i] = f2bf(Wk[i * HDW + h * DKV + d]);
            sWv[d * WSTR + i] = f2bf(Wv[i * HDW + h * DKV + d]);
            sWo[d * WSTR + i] = f2bf(Wo[(h * DKV + i) * HH + d]);
        }
        __syncthreads();

        for (int jb = w; jb < 2 * NQT; jb += NWAVE) {
            const int   isV  = jb >= NQT;
            const int   tile = isV ? jb - NQT : jb;
            const float* X   = isV ? v : k;
            const short* sW  = isV ? sWv : sWk;
            int r = tile * 16 + L15; if (r > TT - 1) r = TT - 1;
            short8 afr[2];
            #pragma unroll
            for (int kt = 0; kt < 2; ++kt) {
                const float* px = X + xbase + (long)r * HH + kt * 32 + quad * 8;
                const float4 x0 = *(const float4*)px;
                const float4 x1 = *(const float4*)(px + 4);
                short8 a;
                a[0]=f2bf(x0.x); a[1]=f2bf(x0.y); a[2]=f2bf(x0.z); a[3]=f2bf(x0.w);
                a[4]=f2bf(x1.x); a[5]=f2bf(x1.y); a[6]=f2bf(x1.z); a[7]=f2bf(x1.w);
                afr[kt] = a;
            }
            #pragma unroll
            for (int nt = 0; nt < 4; ++nt) {
                f32x4 c; c[0]=0.f; c[1]=0.f; c[2]=0.f; c[3]=0.f;
                #pragma unroll
                for (int kt = 0; kt < 2; ++kt) {
                    const short8 bfr = *(const short8*)&sW[(nt*16 + L15) * WSTR + kt*32 + quad*8];
                    c = MFMA32(afr[kt], bfr, c);
                }
                #pragma unroll
                for (int rr = 0; rr < 4; ++rr) {
                    const int s = tile*16 + quad*4 + rr;
                    if (s < TT) {
                        const short bv = f2bf(c[rr]);
                        const int d = nt*16 + L15;
                        if (isV) sVT[d * VSTR + s] = bv;
                        else     sK [s * KSTR + d] = bv;
                    }
                }
            }
        }
        __syncthreads();

        for (int ti = 0; ti < nMy; ++ti) {
            const int tile = myT[ti];
            short8 qa[2];
            {
                int r = tile * 16 + L15; if (r > TT - 1) r = TT - 1;
                short8 afr[2];
                #pragma unroll
                for (int kt = 0; kt < 2; ++kt) {
                    const float* px = q + xbase + (long)r * HH + kt * 32 + quad * 8;
                    const float4 x0 = *(const float4*)px;
                    const float4 x1 = *(const float4*)(px + 4);
                    short8 a;
                    a[0]=f2bf(x0.x); a[1]=f2bf(x0.y); a[2]=f2bf(x0.z); a[3]=f2bf(x0.w);
                    a[4]=f2bf(x1.x); a[5]=f2bf(x1.y); a[6]=f2bf(x1.z); a[7]=f2bf(x1.w);
                    afr[kt] = a;
                }
                #pragma unroll
                for (int nt = 0; nt < 4; ++nt) {
                    f32x4 c; c[0]=0.f; c[1]=0.f; c[2]=0.f; c[3]=0.f;
                    #pragma unroll
                    for (int kt = 0; kt < 2; ++kt) {
                        const short8 bfr = *(const short8*)&sWq[(nt*16 + L15) * WSTR + kt*32 + quad*8];
                        c = MFMA32(afr[kt], bfr, c);
                    }
                    #pragma unroll
                    for (int rr = 0; rr < 4; ++rr)
                        sScrF[w][(quad*4+rr)*KSTR + nt*16 + L15] = f2bf(c[rr] * 0.125f);
                }
                LGKM_BAR();
                qa[0] = *(const short8*)&sScrF[w][L15*KSTR + quad*8];
                qa[1] = *(const short8*)&sScrF[w][L15*KSTR + 32 + quad*8];
            }

            float m[4] = {-3e38f, -3e38f, -3e38f, -3e38f};
            float l[4] = {0.f, 0.f, 0.f, 0.f};
            f32x4 o[4];
            #pragma unroll
            for (int nt = 0; nt < 4; ++nt) { o[nt][0]=0.f; o[nt][1]=0.f; o[nt][2]=0.f; o[nt][3]=0.f; }

            for (int st = 0; st < NST; ++st) {
                f32x4 s0, s1;
                s0[0]=0.f;s0[1]=0.f;s0[2]=0.f;s0[3]=0.f;
                s1[0]=0.f;s1[1]=0.f;s1[2]=0.f;s1[3]=0.f;
                #pragma unroll
                for (int kt = 0; kt < 2; ++kt) {
                    const short8 b0 = *(const short8*)&sK[(st*32      + L15) * KSTR + kt*32 + quad*8];
                    const short8 b1 = *(const short8*)&sK[(st*32 + 16 + L15) * KSTR + kt*32 + quad*8];
                    s0 = MFMA32(qa[kt], b0, s0);
                    s1 = MFMA32(qa[kt], b1, s1);
                }
                if (st == NST - 1) {
                    if (L15 >= 12) { s0[0]=-1e38f; s0[1]=-1e38f; s0[2]=-1e38f; s0[3]=-1e38f; }
                    s1[0]=-1e38f; s1[1]=-1e38f; s1[2]=-1e38f; s1[3]=-1e38f;
                }
                float corr[4];
                #pragma unroll
                for (int rr = 0; rr < 4; ++rr) {
                    float t = fmaxf(s0[rr], s1[rr]);
                    t = fmaxf(t, __shfl_xor(t, 1));
                    t = fmaxf(t, __shfl_xor(t, 2));
                    t = fmaxf(t, __shfl_xor(t, 4));
                    t = fmaxf(t, __shfl_xor(t, 8));
                    const float mn = fmaxf(m[rr], t);
                    corr[rr] = __expf(m[rr] - mn);
                    m[rr] = mn;
                    const float p0 = __expf(s0[rr] - mn);
                    const float p1 = __expf(s1[rr] - mn);
                    float rs = p0 + p1;
                    rs += __shfl_xor(rs, 1);
                    rs += __shfl_xor(rs, 2);
                    rs += __shfl_xor(rs, 4);
                    rs += __shfl_xor(rs, 8);
                    l[rr] = l[rr] * corr[rr] + rs;
                    sScrF[w][(quad*4+rr)*KSTR + L15]      = f2bf(p0);
                    sScrF[w][(quad*4+rr)*KSTR + 16 + L15] = f2bf(p1);
                }
                #pragma unroll
                for (int nt = 0; nt < 4; ++nt) {
                    o[nt][0] *= corr[0]; o[nt][1] *= corr[1];
                    o[nt][2] *= corr[2]; o[nt][3] *= corr[3];
                }
                LGKM_BAR();
                const short8 pa = *(const short8*)&sScrF[w][L15*KSTR + quad*8];
                #pragma unroll
                for (int nt = 0; nt < 4; ++nt) {
                    const short8 vb = *(const short8*)&sVT[(nt*16 + L15) * VSTR + st*32 + quad*8];
                    o[nt] = MFMA32(pa, vb, o[nt]);
                }
            }

            float linv[4];
            #pragma unroll
            for (int rr = 0; rr < 4; ++rr) linv[rr] = 1.f / l[rr];
            #pragma unroll
            for (int nt = 0; nt < 4; ++nt)
                #pragma unroll
                for (int rr = 0; rr < 4; ++rr)
                    sScrF[w][(quad*4+rr)*KSTR + nt*16 + L15] = f2bf(o[nt][rr] * linv[rr]);
            LGKM_BAR();
            const short8 oa0 = *(const short8*)&sScrF[w][L15*KSTR + quad*8];
            const short8 oa1 = *(const short8*)&sScrF[w][L15*KSTR + 32 + quad*8];
            #pragma unroll
            for (int nt = 0; nt < 4; ++nt) {
                const short8 w0 = *(const short8*)&sWo[(nt*16 + L15) * WSTR + quad*8];
                const short8 w1 = *(const short8*)&sWo[(nt*16 + L15) * WSTR + 32 + quad*8];
                y[ti][nt] = MFMA32(oa0, w0, y[ti][nt]);
                y[ti][nt] = MFMA32(oa1, w1, y[ti][nt]);
            }
        }
    }

    for (int ti = 0; ti < nMy; ++ti) {
        const int tile = myT[ti];
        #pragma unroll
        for (int nt = 0; nt < 4; ++nt)
            #pragma unroll
            for (int rr = 0; rr < 4; ++rr) {
                const int row = tile*16 + quad*4 + rr;
                if (row < TT)
                    out[xbase + (long)row * HH + nt*16 + L15] = y[ti][nt][rr];
            }
    }
}

extern "C" void kernel_launch(void* const* d_in, const int* in_sizes, int n_in,
                              void* d_out, int out_size, void* d_ws, size_t ws_size,
                              hipStream_t stream) {
    const float* q  = (const float*)d_in[0];
    const float* k  = (const float*)d_in[1];
    const float* v  = (const float*)d_in[2];
    const float* Wq = (const float*)d_in[3];
    const float* Wk = (const float*)d_in[4];
    const float* Wv = (const float*)d_in[5];
    const float* Wo = (const float*)d_in[6];
    float* out = (float*)d_out;

    if (ws_size >= WS_BYTES) {
        unsigned short* ws = (unsigned short*)d_ws;
        wfrag_kernel<<<96, 64, 0, stream>>>(Wq, Wk, Wv, Wo, ws);
        attn13<<<NB * NJ, 512, 0, stream>>>(q, k, v, ws, out);
    } else {
        mha_mfma<<<NB * NJ, 512, 0, stream>>>(q, k, v, Wq, Wk, Wv, Wo, out);
    }
}